// Round 1
// baseline (169.463 us; speedup 1.0000x reference)
//
#include <hip/hip_runtime.h>
#include <cstdint>
#include <cstddef>

#define B_ 2
#define S_ 2049
#define E_ 512
#define H_ 8
#define WIN_ 1024
#define MROWS (B_*S_)     // 4098
#define SP_ 2176          // padded seq for vT cols
#define GBUFN 4104

typedef unsigned short ushort_t;
typedef __attribute__((ext_vector_type(8))) short bf16x8;   // 8 bf16 (4 VGPRs)
typedef __attribute__((ext_vector_type(4))) float f32x4;

#define MFMA16(a,b,c) __builtin_amdgcn_mfma_f32_16x16x32_bf16(a,b,c,0,0,0)

__device__ __forceinline__ ushort_t f2bf(float f) {          // RNE fp32->bf16
  unsigned int u = __float_as_uint(f);
  u += 0x7fffu + ((u >> 16) & 1u);
  return (ushort_t)(u >> 16);
}
__device__ __forceinline__ float bf2f(ushort_t h) {
  return __uint_as_float(((unsigned int)h) << 16);
}

// ---------------------------------------------------------------------------
// One launch: blocks [0,2049) convert x fp32->bf16 (coalesced float4);
// blocks [2049,3073): W [k][n] -> Wt [n][k] bf16 (z<3) / WoHi (z==3),
// z==3 blocks also zero the gate accumulators.
// ---------------------------------------------------------------------------
__global__ __launch_bounds__(256) void convert_all_kernel(
    const float* __restrict__ x, const float* __restrict__ W0,
    const float* __restrict__ W1, const float* __restrict__ W2,
    const float* __restrict__ W3, ushort_t* __restrict__ xb,
    ushort_t* __restrict__ Wt_all, ushort_t* __restrict__ WoHi,
    float* __restrict__ gacc)
{
  __shared__ float tile[32][33];
  int bid = blockIdx.x;
  if (bid < 2049) {
    int idx = bid * 256 + threadIdx.x;               // exactly MROWS*E_/4
    float4 v = ((const float4*)x)[idx];
    ushort4 o;
    o.x = f2bf(v.x); o.y = f2bf(v.y); o.z = f2bf(v.z); o.w = f2bf(v.w);
    ((ushort4*)xb)[idx] = o;
    return;
  }
  int wid = bid - 2049;
  int z = wid >> 8, rem = wid & 255;
  if (z == 3) {
    int gz = rem * 256 + threadIdx.x;
    if (gz < 2 * GBUFN) gacc[gz] = 0.f;
  }
  const float* W = (z == 0) ? W0 : (z == 1) ? W1 : (z == 2) ? W2 : W3;
  int k0 = (rem >> 4) * 32, n0 = (rem & 15) * 32;
  int r = threadIdx.x >> 5, c = threadIdx.x & 31;
#pragma unroll
  for (int i = 0; i < 4; ++i) {
    int rr = r + i * 8;
    tile[rr][c] = W[(size_t)(k0 + rr) * E_ + n0 + c];
  }
  __syncthreads();
#pragma unroll
  for (int i = 0; i < 4; ++i) {
    int rr = r + i * 8;
    float v = tile[c][rr];                       // = W[k0+c][n0+rr]
    size_t dst = (size_t)(n0 + rr) * E_ + k0 + c;
    if (z < 3) Wt_all[(size_t)z * E_ * E_ + dst] = f2bf(v);
    else       WoHi[dst] = f2bf(v);
  }
}

// ---------------------------------------------------------------------------
// QKV projection, 64x128 tile, 2x2 waves (32x64 each), BK=32, reg-prefetch,
// bf16 xb input (halves A traffic vs fp32 x; no in-loop convert).
// Per-b m-tiling (grid.x=66). z<2: row-major bf16 + fused gate partial dots.
// z==2: LDS-transpose -> coalesced vT[b][h][d][i].
// ---------------------------------------------------------------------------
__global__ __launch_bounds__(256) void gemm_qkv_kernel(
    const ushort_t* __restrict__ xb, const ushort_t* __restrict__ Wt_all,
    const float* __restrict__ bq, const float* __restrict__ bk,
    const float* __restrict__ bv, const float* __restrict__ wg,
    ushort_t* __restrict__ qkb, ushort_t* __restrict__ vT,
    float* __restrict__ gacc)
{
  __shared__ __align__(16) ushort_t As[64][40];
  __shared__ __align__(16) ushort_t Bs[128][40];
  int tid = threadIdx.x;
  int lane = tid & 63, w = tid >> 6;
  int l15 = lane & 15, quad = lane >> 4;
  int wm = (w & 1) * 32, wn = (w >> 1) * 64;
  int z = blockIdx.z;
  const ushort_t* Wt = Wt_all + (size_t)z * E_ * E_;
  const float* bias = (z == 0) ? bq : (z == 1) ? bk : bv;
  int bt = blockIdx.x;               // 0..65; 33 i-tiles per batch
  int bg2 = bt / 33;                 // batch b
  int bm = (bt - bg2 * 33) * 64;     // i-tile base within batch
  int bn = blockIdx.y * 128;
  size_t rowbase = (size_t)bg2 * S_;

  int ar = tid >> 2, acq = (tid & 3) * 8;
  int ai = bm + ar; if (ai >= S_) ai = S_ - 1;
  const ushort_t* ap = xb + (rowbase + ai) * E_ + acq;
  int br = tid >> 1, bcq = (tid & 1) * 16;
  const ushort_t* bp = Wt + (size_t)(bn + br) * E_ + bcq;

  const f32x4 fz = {0.f, 0.f, 0.f, 0.f};
  f32x4 acc[2][4];
#pragma unroll
  for (int mt = 0; mt < 2; ++mt)
#pragma unroll
    for (int nt = 0; nt < 4; ++nt) acc[mt][nt] = fz;

  int4 pa = *(const int4*)ap;
  int4 pb0 = *(const int4*)bp, pb1 = *(const int4*)(bp + 8);

  for (int k0 = 0; k0 < E_; k0 += 32) {
    __syncthreads();
    int kn = (k0 + 32 < E_) ? (k0 + 32) : k0;
    int4 na = *(const int4*)(ap + kn);
    int4 nb0 = *(const int4*)(bp + kn), nb1 = *(const int4*)(bp + kn + 8);
    *(int4*)&As[ar][acq] = pa;
    *(int4*)&Bs[br][bcq] = pb0; *(int4*)&Bs[br][bcq + 8] = pb1;
    __syncthreads();
    bf16x8 a[2], bfr[4];
#pragma unroll
    for (int mt = 0; mt < 2; ++mt) a[mt] = *(const bf16x8*)&As[wm + mt * 16 + l15][quad * 8];
#pragma unroll
    for (int nt = 0; nt < 4; ++nt) bfr[nt] = *(const bf16x8*)&Bs[wn + nt * 16 + l15][quad * 8];
#pragma unroll
    for (int mt = 0; mt < 2; ++mt)
#pragma unroll
      for (int nt = 0; nt < 4; ++nt)
        acc[mt][nt] = MFMA16(a[mt], bfr[nt], acc[mt][nt]);
    pa = na; pb0 = nb0; pb1 = nb1;
  }

  float bb[4];
#pragma unroll
  for (int nt = 0; nt < 4; ++nt) bb[nt] = bias[bn + wn + nt * 16 + l15];

  if (z < 2) {
    ushort_t* C = qkb + (size_t)z * MROWS * E_;
#pragma unroll
    for (int mt = 0; mt < 2; ++mt)
#pragma unroll
      for (int nt = 0; nt < 4; ++nt)
#pragma unroll
        for (int r = 0; r < 4; ++r) {
          int i = bm + wm + mt * 16 + quad * 4 + r;
          if (i < S_)
            C[(rowbase + i) * E_ + bn + wn + nt * 16 + l15] = f2bf(acc[mt][nt][r] + bb[nt]);
        }
    // fused gate partial dots
    const float* wgp = wg + (size_t)z * E_;
    float wv[4];
#pragma unroll
    for (int nt = 0; nt < 4; ++nt) wv[nt] = wgp[bn + wn + nt * 16 + l15];
    float* gp = gacc + (size_t)z * GBUFN;
#pragma unroll
    for (int mt = 0; mt < 2; ++mt)
#pragma unroll
      for (int r = 0; r < 4; ++r) {
        float s = 0.f;
#pragma unroll
        for (int nt = 0; nt < 4; ++nt) s = fmaf(acc[mt][nt][r] + bb[nt], wv[nt], s);
        s += __shfl_xor(s, 1, 16); s += __shfl_xor(s, 2, 16);
        s += __shfl_xor(s, 4, 16); s += __shfl_xor(s, 8, 16);
        int i = bm + wm + mt * 16 + quad * 4 + r;
        if (l15 == 0 && i < S_) atomicAdd(&gp[rowbase + i], s);
      }
  } else {
    // v: LDS transpose (2-way conflicts = free) then coalesced aligned int4
    ushort_t* lt = &Bs[0][0];                    // 64d x 72i tile
    int ti = tid >> 2, tc = (tid & 3) * 16;
#pragma unroll
    for (int hh = 0; hh < 2; ++hh) {
      __syncthreads();
      if ((w >> 1) == hh) {
#pragma unroll
        for (int mt = 0; mt < 2; ++mt)
#pragma unroll
          for (int nt = 0; nt < 4; ++nt) {
            int d = nt * 16 + l15;
#pragma unroll
            for (int r = 0; r < 4; ++r) {
              int il = wm + mt * 16 + quad * 4 + r;
              lt[d * 72 + il] = f2bf(acc[mt][nt][r] + bb[nt]);
            }
          }
      }
      __syncthreads();
      int hg = (bn >> 6) + hh;
      union { int4 q[2]; ushort_t u[16]; } tv;
      tv.q[0] = *(const int4*)&lt[ti * 72 + tc];
      tv.q[1] = *(const int4*)&lt[ti * 72 + tc + 8];
      size_t vrow = ((size_t)(bg2 * H_ + hg) * 64 + ti) * SP_;
#pragma unroll
      for (int c8 = 0; c8 < 2; ++c8) {
        int i2 = bm + tc + c8 * 8;
        if (i2 + 7 < S_) {
          *(int4*)&vT[vrow + i2] = tv.q[c8];
        } else {
#pragma unroll
          for (int e = 0; e < 8; ++e)
            if (i2 + e < S_) vT[vrow + i2 + e] = tv.u[c8 * 8 + e];
        }
      }
    }
  }
}

// ---------------------------------------------------------------------------
// MFMA flash attention, S^T form, fixed-reference softmax, fused combine.
// 512 threads / 8 waves: waves 0-3 = first half of j-window (i-groups 0-3),
// waves 4-7 = second half. Each half double-stages its own K/V tiles in LDS
// (register prefetch), predicated last iteration when halves are uneven.
// After the j-loop the halves merge unnormalized O + l through LDS (reusing
// the V^T buffer), normalize, and emit bf16 hi/lo directly -> no Opart
// round-trip (25.2 MB write + 25.2 MB read removed) and no combine kernel.
// LDS 62.5 KB -> 2 blocks/CU (16 waves). Grid 33*16 = 528, middle-out.
// ---------------------------------------------------------------------------
__global__ __launch_bounds__(512) void attn_kernel(
    const ushort_t* __restrict__ qb, const ushort_t* __restrict__ kb,
    const ushort_t* __restrict__ vT, const float* __restrict__ gq_raw,
    const float* __restrict__ gk_raw, const float* __restrict__ bgate,
    ushort_t* __restrict__ aHi, ushort_t* __restrict__ aLo)
{
  __shared__ __align__(16) ushort_t Ks[2][64][72];    // [half][j][d]
  __shared__ __align__(16) ushort_t Vt[2][64][72];    // [half][d][j]
  __shared__ __align__(16) ushort_t Ps[8][16][72];    // per-wave P [i][j]
  __shared__ __align__(16) float gbs[2][1088];

  int tid = threadIdx.x;
  int lane = tid & 63, w = tid >> 6;
  int l15 = lane & 15, quad = lane >> 4;
  int iw = w & 3, jhalf = w >> 2;
  int t256 = tid & 255;

  // middle-out q-tile order; 16 blocks (bh) per qt
  int sub = blockIdx.x & 15;
  int qidx = blockIdx.x >> 4;
  int off = (qidx + 1) >> 1;
  int qt = 16 + ((qidx & 1) ? -off : off);          // 0..32
  int h = sub & 7, b = sub >> 3;
  int i0 = qt * 64;
  const float LOG2E = 1.44269504f;
  const float coef2 = (-0.5f / (512.f * 512.f)) * LOG2E;
  const float QSC = 0.125f * LOG2E;

  // per-thread q-row
  int i = i0 + iw * 16 + l15;
  int ic = (i < S_) ? i : S_ - 1;
  bf16x8 qf0 = *(const bf16x8*)&qb[((size_t)(b * S_ + ic)) * E_ + h * 64 + quad * 8];
  bf16x8 qf1 = *(const bf16x8*)&qb[((size_t)(b * S_ + ic)) * E_ + h * 64 + 32 + quad * 8];
#pragma unroll
  for (int e = 0; e < 8; ++e) {                     // fold D^-0.5 * log2e into Q
    qf0[e] = (short)f2bf(bf2f((ushort_t)qf0[e]) * QSC);
    qf1[e] = (short)f2bf(bf2f((ushort_t)qf1[e]) * QSC);
  }
  float av = __expf(-(gq_raw[b * S_ + ic] + bgate[0]));
  float fdi = (i < S_) ? (float)i : -1e5f;

  int jlo = i0 - WIN_; if (jlo < 0) jlo = 0;
  int jt_lo = jlo >> 6;
  int jhi = i0 + 63 + WIN_; if (jhi > S_ - 1) jhi = S_ - 1;
  int jt_hi = jhi >> 6;
  int L = jt_hi - jt_lo + 1;                        // 17..33
  int n0 = (L + 1) >> 1, n1 = L - n0;               // n0 >= n1 >= 8
  int myLo = jt_lo + (jhalf ? n0 : 0);
  int cnt = jhalf ? n1 : n0;
  int cmax = n0;
  int jbase = myLo << 6;
  int nwin = cnt << 6;                              // <= 1088

  for (int tt = t256; tt < nwin; tt += 256) {
    int j = jbase + tt; int jc = (j < S_) ? j : S_ - 1;
    gbs[jhalf][tt] = __expf(-gk_raw[b * S_ + jc]);
  }

  // staging maps: K rows=j, V^T rows=d; both 64x64, 2 int4 per thread
  int srow = t256 >> 2, scol = (t256 & 3) * 16;
  const ushort_t* kb_base = kb + (size_t)b * S_ * E_ + h * 64 + scol;
  const ushort_t* vb_base = vT + ((size_t)(b * H_ + h) * 64 + srow) * SP_ + scol;

  int4 ka0, ka1, va0, va1;
  {
    int jc0 = jbase + srow; if (jc0 > S_ - 1) jc0 = S_ - 1;
    const int4* kp = (const int4*)(kb_base + (size_t)jc0 * E_);
    ka0 = kp[0]; ka1 = kp[1];
    const int4* vp = (const int4*)(vb_base + jbase);
    va0 = vp[0]; va1 = vp[1];
  }

  const f32x4 fz = {0.f, 0.f, 0.f, 0.f};
  f32x4 Ov[4] = {fz, fz, fz, fz};
  float l_run = 0.f;

  for (int t = 0; t < cmax; ++t) {
    int act = (t < cnt);
    int j0 = (myLo + t) << 6;
    int4 nk0, nk1, nv0, nv1;
    __syncthreads();
    if (act) {
      int jn = (t + 1 < cnt) ? (j0 + 64) : j0;
      int jcn = jn + srow; if (jcn > S_ - 1) jcn = S_ - 1;
      const int4* kp = (const int4*)(kb_base + (size_t)jcn * E_);
      nk0 = kp[0]; nk1 = kp[1];
      const int4* vp = (const int4*)(vb_base + jn);
      nv0 = vp[0]; nv1 = vp[1];
      *(int4*)&Ks[jhalf][srow][scol] = ka0; *(int4*)&Ks[jhalf][srow][scol + 8] = ka1;
      *(int4*)&Vt[jhalf][srow][scol] = va0; *(int4*)&Vt[jhalf][srow][scol + 8] = va1;
    }
    __syncthreads();
    if (act) {
      // S^T = K . Q^T : lane holds one q-row (i=l15), 16 j's
      f32x4 st[4];
      __builtin_amdgcn_s_setprio(1);
#pragma unroll
      for (int nt = 0; nt < 4; ++nt) {
        bf16x8 kf0 = *(const bf16x8*)&Ks[jhalf][nt * 16 + l15][quad * 8];
        bf16x8 kf1 = *(const bf16x8*)&Ks[jhalf][nt * 16 + l15][32 + quad * 8];
        f32x4 s = MFMA16(kf0, qf0, fz);
        st[nt] = MFMA16(kf1, qf1, s);
      }
      __builtin_amdgcn_s_setprio(0);

      bool full = ((j0 + 63 - i0) <= WIN_) && ((i0 + 63 - j0) <= WIN_)
                  && (j0 + 63 < S_) && (i0 + 63 < S_);
      float ps = 0.f;
      float fq = fdi - (float)(j0 + quad * 4);
      if (full) {
#pragma unroll
        for (int nt = 0; nt < 4; ++nt) {
          f32x4 g4 = *(const f32x4*)&gbs[jhalf][(j0 - jbase) + nt * 16 + quad * 4];
#pragma unroll
          for (int r = 0; r < 4; ++r) {
            float f = fq - (float)(nt * 16 + r);
            float gate = __builtin_amdgcn_rcpf(fmaf(av, g4[r], 1.f));
            float p = __builtin_amdgcn_exp2f(fmaf(f * f, coef2, st[nt][r]) * gate);
            st[nt][r] = p; ps += p;
          }
        }
      } else {
#pragma unroll
        for (int nt = 0; nt < 4; ++nt) {
          f32x4 g4 = *(const f32x4*)&gbs[jhalf][(j0 - jbase) + nt * 16 + quad * 4];
#pragma unroll
          for (int r = 0; r < 4; ++r) {
            int j = j0 + nt * 16 + quad * 4 + r;
            float fj = (j < S_) ? (float)j : 1e5f;
            float f = fdi - fj;
            float gate = __builtin_amdgcn_rcpf(fmaf(av, g4[r], 1.f));
            float t2 = fmaf(f * f, coef2, st[nt][r]) * gate;
            t2 = (__builtin_fabsf(f) <= 1024.f) ? t2 : -1e30f;
            float p = __builtin_amdgcn_exp2f(t2);
            st[nt][r] = p; ps += p;
          }
        }
      }
      ps += __shfl_xor(ps, 16);
      ps += __shfl_xor(ps, 32);
      l_run += ps;

#pragma unroll
      for (int nt = 0; nt < 4; ++nt) {
        uint2 pk;
        pk.x = (unsigned int)f2bf(st[nt][0]) | ((unsigned int)f2bf(st[nt][1]) << 16);
        pk.y = (unsigned int)f2bf(st[nt][2]) | ((unsigned int)f2bf(st[nt][3]) << 16);
        *(uint2*)&Ps[w][l15][nt * 16 + quad * 4] = pk;
      }
      bf16x8 p0 = *(const bf16x8*)&Ps[w][l15][quad * 8];
      bf16x8 p1 = *(const bf16x8*)&Ps[w][l15][32 + quad * 8];
      __builtin_amdgcn_s_setprio(1);
#pragma unroll
      for (int nt = 0; nt < 4; ++nt) {
        bf16x8 v0 = *(const bf16x8*)&Vt[jhalf][nt * 16 + l15][quad * 8];
        bf16x8 v1 = *(const bf16x8*)&Vt[jhalf][nt * 16 + l15][32 + quad * 8];
        Ov[nt] = MFMA16(p0, v0, Ov[nt]);
        Ov[nt] = MFMA16(p1, v1, Ov[nt]);
      }
      __builtin_amdgcn_s_setprio(0);
      ka0 = nk0; ka1 = nk1; va0 = nv0; va1 = nv1;
    }
  }

  // ---- fused combine: merge halves via LDS, normalize, emit bf16 hi/lo ----
  __syncthreads();                                   // all PV reads done
  float* Of = (float*)&Vt[0][0][0];                  // 4 i-groups x 16 x 64 fp32
  float* Lf = Of + 4096;                             // [2][4][16]
  if (jhalf) {
#pragma unroll
    for (int nt = 0; nt < 4; ++nt)
#pragma unroll
      for (int r = 0; r < 4; ++r)
        Of[(iw * 16 + quad * 4 + r) * 64 + nt * 16 + l15] = Ov[nt][r];
  }
  if (lane < 16) Lf[jhalf * 64 + iw * 16 + lane] = l_run;
  __syncthreads();
  if (!jhalf) {
#pragma unroll
    for (int r = 0; r < 4; ++r) {
      int row = quad * 4 + r;
      int irow = i0 + iw * 16 + row;
      if (irow < S_) {
        float lt = Lf[iw * 16 + row] + Lf[64 + iw * 16 + row];
        float inv = 1.f / lt;
#pragma unroll
        for (int nt = 0; nt < 4; ++nt) {
          float o = (Ov[nt][r] + Of[(iw * 16 + row) * 64 + nt * 16 + l15]) * inv;
          ushort_t hi = f2bf(o);
          ushort_t lo = f2bf(o - bf2f(hi));
          size_t oidx = ((size_t)b * S_ + irow) * E_ + h * 64 + nt * 16 + l15;
          aHi[oidx] = hi; aLo[oidx] = lo;
        }
      }
    }
  }
}

// ---------------------------------------------------------------------------
// Output projection, 64x64 tile, 2x2 waves (32x32 each), 2-term split:
// C = (Ahi + Alo) @ Whi + bias (fp32 out). Grid (65,8) = 520 blocks
// (2 blocks/CU vs 1 at the old (65,4)x128 shape), reg-prefetch.
// ---------------------------------------------------------------------------
__global__ __launch_bounds__(256) void gemm_out_kernel(
    const ushort_t* __restrict__ Ahi, const ushort_t* __restrict__ Alo,
    const ushort_t* __restrict__ Whi, const float* __restrict__ bias,
    float* __restrict__ C)
{
  __shared__ __align__(16) ushort_t AsH[64][40];
  __shared__ __align__(16) ushort_t AsL[64][40];
  __shared__ __align__(16) ushort_t BsW[64][40];
  int tid = threadIdx.x;
  int lane = tid & 63, w = tid >> 6;
  int l15 = lane & 15, quad = lane >> 4;
  int wm = (w & 1) * 32, wn = (w >> 1) * 32;
  int bm = blockIdx.x * 64, bn = blockIdx.y * 64;

  int sr = tid >> 2, sc = (tid & 3) * 8;
  int am = bm + sr; if (am >= MROWS) am = MROWS - 1;
  const ushort_t* ahp = Ahi + (size_t)am * E_ + sc;
  const ushort_t* alp = Alo + (size_t)am * E_ + sc;
  const ushort_t* bp = Whi + (size_t)(bn + sr) * E_ + sc;

  const f32x4 fz = {0.f, 0.f, 0.f, 0.f};
  f32x4 acc[2][2];
#pragma unroll
  for (int mt = 0; mt < 2; ++mt)
#pragma unroll
    for (int nt = 0; nt < 2; ++nt) acc[mt][nt] = fz;

  int4 ph = *(const int4*)ahp, pl = *(const int4*)alp;
  int4 pb = *(const int4*)bp;

  for (int k0 = 0; k0 < E_; k0 += 32) {
    __syncthreads();
    int kn = (k0 + 32 < E_) ? (k0 + 32) : k0;
    int4 nh = *(const int4*)(ahp + kn);
    int4 nl = *(const int4*)(alp + kn);
    int4 nb = *(const int4*)(bp + kn);
    *(int4*)&AsH[sr][sc] = ph;
    *(int4*)&AsL[sr][sc] = pl;
    *(int4*)&BsW[sr][sc] = pb;
    __syncthreads();
    bf16x8 ah[2], al[2], bw[2];
#pragma unroll
    for (int mt = 0; mt < 2; ++mt) {
      ah[mt] = *(const bf16x8*)&AsH[wm + mt * 16 + l15][quad * 8];
      al[mt] = *(const bf16x8*)&AsL[wm + mt * 16 + l15][quad * 8];
    }
#pragma unroll
    for (int nt = 0; nt < 2; ++nt) bw[nt] = *(const bf16x8*)&BsW[wn + nt * 16 + l15][quad * 8];
#pragma unroll
    for (int mt = 0; mt < 2; ++mt)
#pragma unroll
      for (int nt = 0; nt < 2; ++nt) {
        acc[mt][nt] = MFMA16(ah[mt], bw[nt], acc[mt][nt]);
        acc[mt][nt] = MFMA16(al[mt], bw[nt], acc[mt][nt]);
      }
    ph = nh; pl = nl; pb = nb;
  }
#pragma unroll
  for (int nt = 0; nt < 2; ++nt) {
    float bb = bias[bn + wn + nt * 16 + l15];
#pragma unroll
    for (int mt = 0; mt < 2; ++mt)
#pragma unroll
      for (int r = 0; r < 4; ++r) {
        int m = bm + wm + mt * 16 + quad * 4 + r;
        if (m < MROWS)
          C[(size_t)m * E_ + bn + wn + nt * 16 + l15] = acc[mt][nt][r] + bb;
      }
  }
}

// ---------------------------------------------------------------------------
extern "C" void kernel_launch(void* const* d_in, const int* in_sizes, int n_in,
                              void* d_out, int out_size, void* d_ws, size_t ws_size,
                              hipStream_t stream) {
  const float* x  = (const float*)d_in[0];
  const float* Wq = (const float*)d_in[1];
  const float* bq = (const float*)d_in[2];
  const float* Wk = (const float*)d_in[3];
  const float* bk = (const float*)d_in[4];
  const float* Wv = (const float*)d_in[5];
  const float* bv = (const float*)d_in[6];
  const float* Wo = (const float*)d_in[7];
  const float* bo = (const float*)d_in[8];
  const float* wg = (const float*)d_in[9];
  const float* bg = (const float*)d_in[10];

  char* p = (char*)d_ws;
  ushort_t* Wt_all = (ushort_t*)p; p += (size_t)3 * E_ * E_ * 2;         // 1.57 MB
  ushort_t* WoHi   = (ushort_t*)p; p += (size_t)E_ * E_ * 2;             // 0.52 MB
  ushort_t* qkb    = (ushort_t*)p; p += (size_t)2 * MROWS * E_ * 2;      // 8.39 MB
  ushort_t* vT     = (ushort_t*)p; p += (size_t)B_ * H_ * 64 * SP_ * 2;  // 4.46 MB
  float*    gacc   = (float*)p;    p += (size_t)2 * GBUFN * 4;           // 33 KB
  ushort_t* xb     = (ushort_t*)p; p += (size_t)MROWS * E_ * 2;          // 4.20 MB
  ushort_t* aHi    = (ushort_t*)p; p += (size_t)MROWS * E_ * 2;          // 4.20 MB
  ushort_t* aLo    = (ushort_t*)p; p += (size_t)MROWS * E_ * 2;          // 4.20 MB
  // total ~27.6 MB (attn writes aHi/aLo while other blocks still read q/k,
  // so they can no longer alias qkb)

  hipLaunchKernelGGL(convert_all_kernel, dim3(3073), dim3(256), 0, stream,
                     x, Wq, Wk, Wv, Wo, xb, Wt_all, WoHi, gacc);
  hipLaunchKernelGGL(gemm_qkv_kernel, dim3(66, 4, 3), dim3(256), 0, stream,
                     xb, Wt_all, bq, bk, bv, wg, qkb, vT, gacc);
  hipLaunchKernelGGL(attn_kernel, dim3(33 * 16), dim3(512), 0, stream,
                     qkb, qkb + (size_t)MROWS * E_, vT, gacc, gacc + GBUFN, bg,
                     aHi, aLo);
  hipLaunchKernelGGL(gemm_out_kernel, dim3(65, 8), dim3(256), 0, stream,
                     aHi, aLo, WoHi, bo, (float*)d_out);
}

// Round 2
// 167.047 us; speedup vs baseline: 1.0145x; 1.0145x over previous
//
#include <hip/hip_runtime.h>
#include <cstdint>
#include <cstddef>

#define B_ 2
#define S_ 2049
#define E_ 512
#define H_ 8
#define WIN_ 1024
#define MROWS (B_*S_)     // 4098
#define SP_ 2176          // padded seq for vT cols
#define GBUFN 4104
#define BHS_ (B_*H_*S_)   // 32784

typedef unsigned short ushort_t;
typedef __attribute__((ext_vector_type(8))) short bf16x8;   // 8 bf16 (4 VGPRs)
typedef __attribute__((ext_vector_type(4))) float f32x4;

#define MFMA16(a,b,c) __builtin_amdgcn_mfma_f32_16x16x32_bf16(a,b,c,0,0,0)

__device__ __forceinline__ ushort_t f2bf(float f) {          // RNE fp32->bf16
  unsigned int u = __float_as_uint(f);
  u += 0x7fffu + ((u >> 16) & 1u);
  return (ushort_t)(u >> 16);
}
__device__ __forceinline__ float bf2f(ushort_t h) {
  return __uint_as_float(((unsigned int)h) << 16);
}

// ---------------------------------------------------------------------------
// One launch: blocks [0,2049) convert x fp32->bf16 (coalesced float4) AND
// zero the fp32 O accumulator (exact float4 coverage: 2049*256 == BHS_*64/4);
// blocks [2049,3073): W [k][n] -> Wt [n][k] bf16 (z<3) / WoHi (z==3),
// z==3 blocks also zero the gate accumulators and Lacc.
// ---------------------------------------------------------------------------
__global__ __launch_bounds__(256) void convert_all_kernel(
    const float* __restrict__ x, const float* __restrict__ W0,
    const float* __restrict__ W1, const float* __restrict__ W2,
    const float* __restrict__ W3, ushort_t* __restrict__ xb,
    ushort_t* __restrict__ Wt_all, ushort_t* __restrict__ WoHi,
    float* __restrict__ gacc, float* __restrict__ Oacc,
    float* __restrict__ Lacc)
{
  __shared__ float tile[32][33];
  int bid = blockIdx.x;
  if (bid < 2049) {
    int idx = bid * 256 + threadIdx.x;               // exactly MROWS*E_/4
    float4 v = ((const float4*)x)[idx];
    ushort4 o;
    o.x = f2bf(v.x); o.y = f2bf(v.y); o.z = f2bf(v.z); o.w = f2bf(v.w);
    ((ushort4*)xb)[idx] = o;
    float4 z4 = {0.f, 0.f, 0.f, 0.f};
    ((float4*)Oacc)[idx] = z4;                       // exactly BHS_*64 floats
    return;
  }
  int wid = bid - 2049;
  int z = wid >> 8, rem = wid & 255;
  if (z == 3) {
    int gz = rem * 256 + threadIdx.x;                // up to 65536 ids
    if (gz < 2 * GBUFN) gacc[gz] = 0.f;
    if (gz < BHS_) Lacc[gz] = 0.f;
  }
  const float* W = (z == 0) ? W0 : (z == 1) ? W1 : (z == 2) ? W2 : W3;
  int k0 = (rem >> 4) * 32, n0 = (rem & 15) * 32;
  int r = threadIdx.x >> 5, c = threadIdx.x & 31;
#pragma unroll
  for (int i = 0; i < 4; ++i) {
    int rr = r + i * 8;
    tile[rr][c] = W[(size_t)(k0 + rr) * E_ + n0 + c];
  }
  __syncthreads();
#pragma unroll
  for (int i = 0; i < 4; ++i) {
    int rr = r + i * 8;
    float v = tile[c][rr];                       // = W[k0+c][n0+rr]
    size_t dst = (size_t)(n0 + rr) * E_ + k0 + c;
    if (z < 3) Wt_all[(size_t)z * E_ * E_ + dst] = f2bf(v);
    else       WoHi[dst] = f2bf(v);
  }
}

// ---------------------------------------------------------------------------
// QKV projection, 64x128 tile, 2x2 waves (32x64 each), BK=32, reg-prefetch,
// bf16 xb input (halves A traffic vs fp32 x; no in-loop convert).
// Per-b m-tiling (grid.x=66). z<2: row-major bf16 + fused gate partial dots.
// z==2: LDS-transpose -> coalesced vT[b][h][d][i].
// ---------------------------------------------------------------------------
__global__ __launch_bounds__(256) void gemm_qkv_kernel(
    const ushort_t* __restrict__ xb, const ushort_t* __restrict__ Wt_all,
    const float* __restrict__ bq, const float* __restrict__ bk,
    const float* __restrict__ bv, const float* __restrict__ wg,
    ushort_t* __restrict__ qkb, ushort_t* __restrict__ vT,
    float* __restrict__ gacc)
{
  __shared__ __align__(16) ushort_t As[64][40];
  __shared__ __align__(16) ushort_t Bs[128][40];
  int tid = threadIdx.x;
  int lane = tid & 63, w = tid >> 6;
  int l15 = lane & 15, quad = lane >> 4;
  int wm = (w & 1) * 32, wn = (w >> 1) * 64;
  int z = blockIdx.z;
  const ushort_t* Wt = Wt_all + (size_t)z * E_ * E_;
  const float* bias = (z == 0) ? bq : (z == 1) ? bk : bv;
  int bt = blockIdx.x;               // 0..65; 33 i-tiles per batch
  int bg2 = bt / 33;                 // batch b
  int bm = (bt - bg2 * 33) * 64;     // i-tile base within batch
  int bn = blockIdx.y * 128;
  size_t rowbase = (size_t)bg2 * S_;

  int ar = tid >> 2, acq = (tid & 3) * 8;
  int ai = bm + ar; if (ai >= S_) ai = S_ - 1;
  const ushort_t* ap = xb + (rowbase + ai) * E_ + acq;
  int br = tid >> 1, bcq = (tid & 1) * 16;
  const ushort_t* bp = Wt + (size_t)(bn + br) * E_ + bcq;

  const f32x4 fz = {0.f, 0.f, 0.f, 0.f};
  f32x4 acc[2][4];
#pragma unroll
  for (int mt = 0; mt < 2; ++mt)
#pragma unroll
    for (int nt = 0; nt < 4; ++nt) acc[mt][nt] = fz;

  int4 pa = *(const int4*)ap;
  int4 pb0 = *(const int4*)bp, pb1 = *(const int4*)(bp + 8);

  for (int k0 = 0; k0 < E_; k0 += 32) {
    __syncthreads();
    int kn = (k0 + 32 < E_) ? (k0 + 32) : k0;
    int4 na = *(const int4*)(ap + kn);
    int4 nb0 = *(const int4*)(bp + kn), nb1 = *(const int4*)(bp + kn + 8);
    *(int4*)&As[ar][acq] = pa;
    *(int4*)&Bs[br][bcq] = pb0; *(int4*)&Bs[br][bcq + 8] = pb1;
    __syncthreads();
    bf16x8 a[2], bfr[4];
#pragma unroll
    for (int mt = 0; mt < 2; ++mt) a[mt] = *(const bf16x8*)&As[wm + mt * 16 + l15][quad * 8];
#pragma unroll
    for (int nt = 0; nt < 4; ++nt) bfr[nt] = *(const bf16x8*)&Bs[wn + nt * 16 + l15][quad * 8];
#pragma unroll
    for (int mt = 0; mt < 2; ++mt)
#pragma unroll
      for (int nt = 0; nt < 4; ++nt)
        acc[mt][nt] = MFMA16(a[mt], bfr[nt], acc[mt][nt]);
    pa = na; pb0 = nb0; pb1 = nb1;
  }

  float bb[4];
#pragma unroll
  for (int nt = 0; nt < 4; ++nt) bb[nt] = bias[bn + wn + nt * 16 + l15];

  if (z < 2) {
    ushort_t* C = qkb + (size_t)z * MROWS * E_;
#pragma unroll
    for (int mt = 0; mt < 2; ++mt)
#pragma unroll
      for (int nt = 0; nt < 4; ++nt)
#pragma unroll
        for (int r = 0; r < 4; ++r) {
          int i = bm + wm + mt * 16 + quad * 4 + r;
          if (i < S_)
            C[(rowbase + i) * E_ + bn + wn + nt * 16 + l15] = f2bf(acc[mt][nt][r] + bb[nt]);
        }
    // fused gate partial dots
    const float* wgp = wg + (size_t)z * E_;
    float wv[4];
#pragma unroll
    for (int nt = 0; nt < 4; ++nt) wv[nt] = wgp[bn + wn + nt * 16 + l15];
    float* gp = gacc + (size_t)z * GBUFN;
#pragma unroll
    for (int mt = 0; mt < 2; ++mt)
#pragma unroll
      for (int r = 0; r < 4; ++r) {
        float s = 0.f;
#pragma unroll
        for (int nt = 0; nt < 4; ++nt) s = fmaf(acc[mt][nt][r] + bb[nt], wv[nt], s);
        s += __shfl_xor(s, 1, 16); s += __shfl_xor(s, 2, 16);
        s += __shfl_xor(s, 4, 16); s += __shfl_xor(s, 8, 16);
        int i = bm + wm + mt * 16 + quad * 4 + r;
        if (l15 == 0 && i < S_) atomicAdd(&gp[rowbase + i], s);
      }
  } else {
    // v: LDS transpose (2-way conflicts = free) then coalesced aligned int4
    ushort_t* lt = &Bs[0][0];                    // 64d x 72i tile
    int ti = tid >> 2, tc = (tid & 3) * 16;
#pragma unroll
    for (int hh = 0; hh < 2; ++hh) {
      __syncthreads();
      if ((w >> 1) == hh) {
#pragma unroll
        for (int mt = 0; mt < 2; ++mt)
#pragma unroll
          for (int nt = 0; nt < 4; ++nt) {
            int d = nt * 16 + l15;
#pragma unroll
            for (int r = 0; r < 4; ++r) {
              int il = wm + mt * 16 + quad * 4 + r;
              lt[d * 72 + il] = f2bf(acc[mt][nt][r] + bb[nt]);
            }
          }
      }
      __syncthreads();
      int hg = (bn >> 6) + hh;
      union { int4 q[2]; ushort_t u[16]; } tv;
      tv.q[0] = *(const int4*)&lt[ti * 72 + tc];
      tv.q[1] = *(const int4*)&lt[ti * 72 + tc + 8];
      size_t vrow = ((size_t)(bg2 * H_ + hg) * 64 + ti) * SP_;
#pragma unroll
      for (int c8 = 0; c8 < 2; ++c8) {
        int i2 = bm + tc + c8 * 8;
        if (i2 + 7 < S_) {
          *(int4*)&vT[vrow + i2] = tv.q[c8];
        } else {
#pragma unroll
          for (int e = 0; e < 8; ++e)
            if (i2 + e < S_) vT[vrow + i2 + e] = tv.u[c8 * 8 + e];
        }
      }
    }
  }
}

// ---------------------------------------------------------------------------
// MFMA flash attention, S^T form, fixed-reference softmax, thirds split
// (R0 structure: 1584 blocks x 256 thr, 5 blocks/CU — proven 45.8 µs).
// Partials now accumulate via fp32 atomicAdd into a single Oacc/Lacc slot,
// so the combine kernel is gone (normalize fused into gemm_out).
// setprio(1) wraps both MFMA clusters (T5, +4-7% on attn per m191).
// ---------------------------------------------------------------------------
__global__ __launch_bounds__(256) void attn_kernel(
    const ushort_t* __restrict__ qb, const ushort_t* __restrict__ kb,
    const ushort_t* __restrict__ vT, const float* __restrict__ gq_raw,
    const float* __restrict__ gk_raw, const float* __restrict__ bgate,
    float* __restrict__ Oacc, float* __restrict__ Lacc)
{
  __shared__ __align__(16) ushort_t Ks[64][72];    // [j][d]
  __shared__ __align__(16) ushort_t Vt[64][72];    // [d][j]
  __shared__ __align__(16) ushort_t Ps[4][16][72]; // per-wave P [i][j]
  __shared__ float gbs[704];

  int tid = threadIdx.x;
  int lane = tid & 63, w = tid >> 6;
  int l15 = lane & 15, quad = lane >> 4;

  // middle-out q-tile order; 48 blocks (16 bh x 3 thirds) per qt
  int sub = blockIdx.x % 48;
  int qidx = blockIdx.x / 48;
  int off = (qidx + 1) >> 1;
  int qt = 16 + ((qidx & 1) ? -off : off);          // 0..32
  int bh = sub & 15, third = sub >> 4;
  int h = bh & 7, b = bh >> 3;
  int i0 = qt * 64;
  const float LOG2E = 1.44269504f;
  const float coef2 = (-0.5f / (512.f * 512.f)) * LOG2E;
  const float QSC = 0.125f * LOG2E;

  // per-thread q-row
  int i = i0 + w * 16 + l15;
  int ic = (i < S_) ? i : S_ - 1;
  bf16x8 qf0 = *(const bf16x8*)&qb[((size_t)(b * S_ + ic)) * E_ + h * 64 + quad * 8];
  bf16x8 qf1 = *(const bf16x8*)&qb[((size_t)(b * S_ + ic)) * E_ + h * 64 + 32 + quad * 8];
#pragma unroll
  for (int e = 0; e < 8; ++e) {                     // fold D^-0.5 * log2e into Q
    qf0[e] = (short)f2bf(bf2f((ushort_t)qf0[e]) * QSC);
    qf1[e] = (short)f2bf(bf2f((ushort_t)qf1[e]) * QSC);
  }
  float av = __expf(-(gq_raw[b * S_ + ic] + bgate[0]));
  float fdi = (i < S_) ? (float)i : -1e5f;

  int jlo = i0 - WIN_; if (jlo < 0) jlo = 0;
  int jt_lo = jlo >> 6;
  int jhi = i0 + 63 + WIN_; if (jhi > S_ - 1) jhi = S_ - 1;
  int jt_hi = jhi >> 6;
  int L = jt_hi - jt_lo + 1;                        // 17..33
  int n0 = (L + 2) / 3, n1 = (L + 1) / 3;
  int myLo = jt_lo + ((third == 0) ? 0 : (third == 1) ? n0 : n0 + n1);
  int cnt = (third == 0) ? n0 : (third == 1) ? n1 : L - n0 - n1;
  int myHi = myLo + cnt - 1;
  int jbase = myLo << 6;
  int nwin = cnt << 6;                              // <= 704

  for (int tt = tid; tt < nwin; tt += 256) {
    int j = jbase + tt; int jc = (j < S_) ? j : S_ - 1;
    gbs[tt] = __expf(-gk_raw[b * S_ + jc]);
  }

  // staging maps: K rows=j, V^T rows=d; both 64x64, 2 int4 per thread
  int srow = tid >> 2, scol = (tid & 3) * 16;
  const ushort_t* kb_base = kb + (size_t)b * S_ * E_ + h * 64 + scol;
  const ushort_t* vb_base = vT + ((size_t)(b * H_ + h) * 64 + srow) * SP_ + scol;

  int4 ka0, ka1, va0, va1;
  {
    int jc0 = jbase + srow; if (jc0 > S_ - 1) jc0 = S_ - 1;
    const int4* kp = (const int4*)(kb_base + (size_t)jc0 * E_);
    ka0 = kp[0]; ka1 = kp[1];
    const int4* vp = (const int4*)(vb_base + jbase);
    va0 = vp[0]; va1 = vp[1];
  }

  const f32x4 fz = {0.f, 0.f, 0.f, 0.f};
  f32x4 Ov[4] = {fz, fz, fz, fz};
  float l_run = 0.f;

  for (int jt = myLo; jt <= myHi; ++jt) {
    int j0 = jt << 6;
    __syncthreads();
    int jn = (jt < myHi) ? ((jt + 1) << 6) : j0;
    int jcn = jn + srow; if (jcn > S_ - 1) jcn = S_ - 1;
    const int4* kp = (const int4*)(kb_base + (size_t)jcn * E_);
    int4 nk0 = kp[0], nk1 = kp[1];
    const int4* vp = (const int4*)(vb_base + jn);
    int4 nv0 = vp[0], nv1 = vp[1];
    *(int4*)&Ks[srow][scol] = ka0; *(int4*)&Ks[srow][scol + 8] = ka1;
    *(int4*)&Vt[srow][scol] = va0; *(int4*)&Vt[srow][scol + 8] = va1;
    __syncthreads();

    // S^T = K . Q^T : lane holds one q-row (i=l15), 16 j's
    f32x4 st[4];
    __builtin_amdgcn_s_setprio(1);
#pragma unroll
    for (int nt = 0; nt < 4; ++nt) {
      bf16x8 kf0 = *(const bf16x8*)&Ks[nt * 16 + l15][quad * 8];
      bf16x8 kf1 = *(const bf16x8*)&Ks[nt * 16 + l15][32 + quad * 8];
      f32x4 s = MFMA16(kf0, qf0, fz);
      st[nt] = MFMA16(kf1, qf1, s);
    }
    __builtin_amdgcn_s_setprio(0);

    bool full = ((j0 + 63 - i0) <= WIN_) && ((i0 + 63 - j0) <= WIN_)
                && (j0 + 63 < S_) && (i0 + 63 < S_);
    float ps = 0.f;
    float fq = fdi - (float)(j0 + quad * 4);
    if (full) {
#pragma unroll
      for (int nt = 0; nt < 4; ++nt) {
        f32x4 g4 = *(const f32x4*)&gbs[(j0 - jbase) + nt * 16 + quad * 4];
#pragma unroll
        for (int r = 0; r < 4; ++r) {
          float f = fq - (float)(nt * 16 + r);
          float gate = __builtin_amdgcn_rcpf(fmaf(av, g4[r], 1.f));
          float p = __builtin_amdgcn_exp2f(fmaf(f * f, coef2, st[nt][r]) * gate);
          st[nt][r] = p; ps += p;
        }
      }
    } else {
#pragma unroll
      for (int nt = 0; nt < 4; ++nt) {
        f32x4 g4 = *(const f32x4*)&gbs[(j0 - jbase) + nt * 16 + quad * 4];
#pragma unroll
        for (int r = 0; r < 4; ++r) {
          int j = j0 + nt * 16 + quad * 4 + r;
          float fj = (j < S_) ? (float)j : 1e5f;
          float f = fdi - fj;
          float gate = __builtin_amdgcn_rcpf(fmaf(av, g4[r], 1.f));
          float t = fmaf(f * f, coef2, st[nt][r]) * gate;
          t = (__builtin_fabsf(f) <= 1024.f) ? t : -1e30f;
          float p = __builtin_amdgcn_exp2f(t);
          st[nt][r] = p; ps += p;
        }
      }
    }
    ps += __shfl_xor(ps, 16);
    ps += __shfl_xor(ps, 32);
    l_run += ps;

#pragma unroll
    for (int nt = 0; nt < 4; ++nt) {
      uint2 pk;
      pk.x = (unsigned int)f2bf(st[nt][0]) | ((unsigned int)f2bf(st[nt][1]) << 16);
      pk.y = (unsigned int)f2bf(st[nt][2]) | ((unsigned int)f2bf(st[nt][3]) << 16);
      *(uint2*)&Ps[w][l15][nt * 16 + quad * 4] = pk;
    }
    bf16x8 p0 = *(const bf16x8*)&Ps[w][l15][quad * 8];
    bf16x8 p1 = *(const bf16x8*)&Ps[w][l15][32 + quad * 8];
    __builtin_amdgcn_s_setprio(1);
#pragma unroll
    for (int nt = 0; nt < 4; ++nt) {
      bf16x8 v0 = *(const bf16x8*)&Vt[nt * 16 + l15][quad * 8];
      bf16x8 v1 = *(const bf16x8*)&Vt[nt * 16 + l15][32 + quad * 8];
      Ov[nt] = MFMA16(p0, v0, Ov[nt]);
      Ov[nt] = MFMA16(p1, v1, Ov[nt]);
    }
    __builtin_amdgcn_s_setprio(0);
    ka0 = nk0; ka1 = nk1; va0 = nv0; va1 = nv1;
  }

  // accumulate unnormalized partials (fp32 atomics, 3 writers per location)
  if (lane < 16) {
    int irow = i0 + w * 16 + lane;
    if (irow < S_)
      atomicAdd(&Lacc[(size_t)(b * H_ + h) * S_ + irow], l_run);
  }
#pragma unroll
  for (int r = 0; r < 4; ++r) {
    int irow = i0 + w * 16 + quad * 4 + r;
    if (irow < S_) {
      float* op = &Oacc[((size_t)(b * H_ + h) * S_ + irow) * 64];
#pragma unroll
      for (int nt = 0; nt < 4; ++nt)
        atomicAdd(&op[nt * 16 + l15], Ov[nt][r]);
    }
  }
}

// ---------------------------------------------------------------------------
// Output projection with fused combine: A-staging reads fp32 Oacc (L3-hot),
// normalizes by 1/Lacc, splits to bf16 hi/lo in-register, stages both, then
// C = (Ahi + Alo) @ Whi + bias (fp32 out). 64x128 tile, grid (65,4).
// Replaces the separate combine kernel (one fewer launch; the 59 MB combine
// round-trip becomes L3 reads hidden under MFMA).
// ---------------------------------------------------------------------------
__global__ __launch_bounds__(256) void gemm_out_kernel(
    const float* __restrict__ Oacc, const float* __restrict__ Lacc,
    const ushort_t* __restrict__ Whi, const float* __restrict__ bias,
    float* __restrict__ C)
{
  __shared__ __align__(16) ushort_t AsH[64][40];
  __shared__ __align__(16) ushort_t AsL[64][40];
  __shared__ __align__(16) ushort_t BsW[128][40];
  int tid = threadIdx.x;
  int lane = tid & 63, w = tid >> 6;
  int l15 = lane & 15, quad = lane >> 4;
  int wm = (w & 1) * 32, wn = (w >> 1) * 64;
  int bm = blockIdx.x * 64, bn = blockIdx.y * 128;

  int sr = tid >> 2, sc = (tid & 3) * 8;
  int am = bm + sr; if (am >= MROWS) am = MROWS - 1;
  int ab = (am >= S_) ? 1 : 0;
  int ai = am - ab * S_;
  size_t obase = (size_t)(ab * H_) * S_;
  int br = tid >> 1, bc = (tid & 1) * 16;
  const ushort_t* bp = Whi + (size_t)(bn + br) * E_ + bc;

  const f32x4 fz = {0.f, 0.f, 0.f, 0.f};
  f32x4 acc[2][4];
#pragma unroll
  for (int mt = 0; mt < 2; ++mt)
#pragma unroll
    for (int nt = 0; nt < 4; ++nt) acc[mt][nt] = fz;

  float4 pa0, pa1; float plv;
  {
    int k = sc;                                   // k0 = 0
    int hh = k >> 6, dd = k & 63;
    const float* oa = Oacc + (obase + (size_t)hh * S_ + ai) * 64 + dd;
    pa0 = *(const float4*)oa; pa1 = *(const float4*)(oa + 4);
    plv = Lacc[obase + (size_t)hh * S_ + ai];
  }
  int4 pb0 = *(const int4*)bp, pb1 = *(const int4*)(bp + 8);

  for (int k0 = 0; k0 < E_; k0 += 32) {
    __syncthreads();
    int kn = (k0 + 32 < E_) ? (k0 + 32) : k0;
    float4 na0, na1; float nlv;
    {
      int k = kn + sc;
      int hh = k >> 6, dd = k & 63;
      const float* oa = Oacc + (obase + (size_t)hh * S_ + ai) * 64 + dd;
      na0 = *(const float4*)oa; na1 = *(const float4*)(oa + 4);
      nlv = Lacc[obase + (size_t)hh * S_ + ai];
    }
    int4 nb0 = *(const int4*)(bp + kn), nb1 = *(const int4*)(bp + kn + 8);

    // normalize + hi/lo split current A slice, stage to LDS
    float inv = 1.f / plv;
    float oe[8] = {pa0.x, pa0.y, pa0.z, pa0.w, pa1.x, pa1.y, pa1.z, pa1.w};
    union { int4 q; ushort_t u[8]; } uh, ul;
#pragma unroll
    for (int e = 0; e < 8; ++e) {
      float o = oe[e] * inv;
      ushort_t hi = f2bf(o);
      uh.u[e] = hi;
      ul.u[e] = f2bf(o - bf2f(hi));
    }
    *(int4*)&AsH[sr][sc] = uh.q;
    *(int4*)&AsL[sr][sc] = ul.q;
    *(int4*)&BsW[br][bc] = pb0; *(int4*)&BsW[br][bc + 8] = pb1;
    __syncthreads();
    bf16x8 ah[2], al[2], bw[4];
#pragma unroll
    for (int mt = 0; mt < 2; ++mt) {
      ah[mt] = *(const bf16x8*)&AsH[wm + mt * 16 + l15][quad * 8];
      al[mt] = *(const bf16x8*)&AsL[wm + mt * 16 + l15][quad * 8];
    }
#pragma unroll
    for (int nt = 0; nt < 4; ++nt) bw[nt] = *(const bf16x8*)&BsW[wn + nt * 16 + l15][quad * 8];
#pragma unroll
    for (int mt = 0; mt < 2; ++mt)
#pragma unroll
      for (int nt = 0; nt < 4; ++nt) {
        acc[mt][nt] = MFMA16(ah[mt], bw[nt], acc[mt][nt]);
        acc[mt][nt] = MFMA16(al[mt], bw[nt], acc[mt][nt]);
      }
    pa0 = na0; pa1 = na1; plv = nlv; pb0 = nb0; pb1 = nb1;
  }
#pragma unroll
  for (int nt = 0; nt < 4; ++nt) {
    float bb = bias[bn + wn + nt * 16 + l15];
#pragma unroll
    for (int mt = 0; mt < 2; ++mt)
#pragma unroll
      for (int r = 0; r < 4; ++r) {
        int m = bm + wm + mt * 16 + quad * 4 + r;
        if (m < MROWS)
          C[(size_t)m * E_ + bn + wn + nt * 16 + l15] = acc[mt][nt][r] + bb;
      }
  }
}

// ---------------------------------------------------------------------------
extern "C" void kernel_launch(void* const* d_in, const int* in_sizes, int n_in,
                              void* d_out, int out_size, void* d_ws, size_t ws_size,
                              hipStream_t stream) {
  const float* x  = (const float*)d_in[0];
  const float* Wq = (const float*)d_in[1];
  const float* bq = (const float*)d_in[2];
  const float* Wk = (const float*)d_in[3];
  const float* bk = (const float*)d_in[4];
  const float* Wv = (const float*)d_in[5];
  const float* bv = (const float*)d_in[6];
  const float* Wo = (const float*)d_in[7];
  const float* bo = (const float*)d_in[8];
  const float* wg = (const float*)d_in[9];
  const float* bg = (const float*)d_in[10];

  char* p = (char*)d_ws;
  ushort_t* Wt_all = (ushort_t*)p; p += (size_t)3 * E_ * E_ * 2;         // 1.57 MB
  ushort_t* WoHi   = (ushort_t*)p; p += (size_t)E_ * E_ * 2;             // 0.52 MB
  ushort_t* qkb    = (ushort_t*)p; p += (size_t)2 * MROWS * E_ * 2;      // 8.39 MB
  ushort_t* vT     = (ushort_t*)p; p += (size_t)B_ * H_ * 64 * SP_ * 2;  // 4.46 MB
  float*    gacc   = (float*)p;    p += (size_t)2 * GBUFN * 4;           // 33 KB
  ushort_t* xb     = (ushort_t*)p; p += (size_t)MROWS * E_ * 2;          // 4.20 MB
  float*    Oacc   = (float*)p;    p += (size_t)BHS_ * 64 * 4;           // 8.39 MB
  float*    Lacc   = (float*)p;    p += (size_t)BHS_ * 4;                // 0.13 MB
  // total ~27.7 MB

  hipLaunchKernelGGL(convert_all_kernel, dim3(3073), dim3(256), 0, stream,
                     x, Wq, Wk, Wv, Wo, xb, Wt_all, WoHi, gacc, Oacc, Lacc);
  hipLaunchKernelGGL(gemm_qkv_kernel, dim3(66, 4, 3), dim3(256), 0, stream,
                     xb, Wt_all, bq, bk, bv, wg, qkb, vT, gacc);
  hipLaunchKernelGGL(attn_kernel, dim3(33 * 48), dim3(256), 0, stream,
                     qkb, qkb + (size_t)MROWS * E_, vT, gacc, gacc + GBUFN, bg,
                     Oacc, Lacc);
  hipLaunchKernelGGL(gemm_out_kernel, dim3(65, 4), dim3(256), 0, stream,
                     Oacc, Lacc, WoHi, bo, (float*)d_out);
}

// Round 3
// 162.867 us; speedup vs baseline: 1.0405x; 1.0257x over previous
//
#include <hip/hip_runtime.h>
#include <cstdint>
#include <cstddef>

#define B_ 2
#define S_ 2049
#define E_ 512
#define H_ 8
#define WIN_ 1024
#define MROWS (B_*S_)     // 4098
#define SP_ 2176          // padded seq for vT cols
#define GBUFN 4104
#define BHS_ (B_*H_*S_)   // 32784

typedef unsigned short ushort_t;
typedef __attribute__((ext_vector_type(8))) short bf16x8;   // 8 bf16 (4 VGPRs)
typedef __attribute__((ext_vector_type(4))) float f32x4;

#define MFMA16(a,b,c) __builtin_amdgcn_mfma_f32_16x16x32_bf16(a,b,c,0,0,0)

__device__ __forceinline__ ushort_t f2bf(float f) {          // RNE fp32->bf16
  unsigned int u = __float_as_uint(f);
  u += 0x7fffu + ((u >> 16) & 1u);
  return (ushort_t)(u >> 16);
}
__device__ __forceinline__ float bf2f(ushort_t h) {
  return __uint_as_float(((unsigned int)h) << 16);
}

// ---------------------------------------------------------------------------
// One launch: blocks [0,2049) convert x fp32->bf16 (coalesced float4);
// blocks [2049,3073): W [k][n] -> Wt [n][k] bf16 (z<3) / WoHi (z==3),
// z==3 blocks also zero the gate accumulators.
// ---------------------------------------------------------------------------
__global__ __launch_bounds__(256) void convert_all_kernel(
    const float* __restrict__ x, const float* __restrict__ W0,
    const float* __restrict__ W1, const float* __restrict__ W2,
    const float* __restrict__ W3, ushort_t* __restrict__ xb,
    ushort_t* __restrict__ Wt_all, ushort_t* __restrict__ WoHi,
    float* __restrict__ gacc)
{
  __shared__ float tile[32][33];
  int bid = blockIdx.x;
  if (bid < 2049) {
    int idx = bid * 256 + threadIdx.x;               // exactly MROWS*E_/4
    float4 v = ((const float4*)x)[idx];
    ushort4 o;
    o.x = f2bf(v.x); o.y = f2bf(v.y); o.z = f2bf(v.z); o.w = f2bf(v.w);
    ((ushort4*)xb)[idx] = o;
    return;
  }
  int wid = bid - 2049;
  int z = wid >> 8, rem = wid & 255;
  if (z == 3) {
    int gz = rem * 256 + threadIdx.x;
    if (gz < 2 * GBUFN) gacc[gz] = 0.f;
  }
  const float* W = (z == 0) ? W0 : (z == 1) ? W1 : (z == 2) ? W2 : W3;
  int k0 = (rem >> 4) * 32, n0 = (rem & 15) * 32;
  int r = threadIdx.x >> 5, c = threadIdx.x & 31;
#pragma unroll
  for (int i = 0; i < 4; ++i) {
    int rr = r + i * 8;
    tile[rr][c] = W[(size_t)(k0 + rr) * E_ + n0 + c];
  }
  __syncthreads();
#pragma unroll
  for (int i = 0; i < 4; ++i) {
    int rr = r + i * 8;
    float v = tile[c][rr];                       // = W[k0+c][n0+rr]
    size_t dst = (size_t)(n0 + rr) * E_ + k0 + c;
    if (z < 3) Wt_all[(size_t)z * E_ * E_ + dst] = f2bf(v);
    else       WoHi[dst] = f2bf(v);
  }
}

// ---------------------------------------------------------------------------
// QKV projection, 64x128 tile, 2x2 waves (32x64 each), BK=64 (8 K-steps,
// half the barriers of BK=32; 16 MFMA/wave/step), reg-prefetch, bf16 xb.
// Per-b m-tiling (grid.x=66). z<2: row-major bf16 + fused gate partial dots.
// z==2: LDS-transpose -> coalesced vT[b][h][d][i].
// ---------------------------------------------------------------------------
__global__ __launch_bounds__(256) void gemm_qkv_kernel(
    const ushort_t* __restrict__ xb, const ushort_t* __restrict__ Wt_all,
    const float* __restrict__ bq, const float* __restrict__ bk,
    const float* __restrict__ bv, const float* __restrict__ wg,
    ushort_t* __restrict__ qkb, ushort_t* __restrict__ vT,
    float* __restrict__ gacc)
{
  __shared__ __align__(16) ushort_t As[64][72];
  __shared__ __align__(16) ushort_t Bs[128][72];
  int tid = threadIdx.x;
  int lane = tid & 63, w = tid >> 6;
  int l15 = lane & 15, quad = lane >> 4;
  int wm = (w & 1) * 32, wn = (w >> 1) * 64;
  int z = blockIdx.z;
  const ushort_t* Wt = Wt_all + (size_t)z * E_ * E_;
  const float* bias = (z == 0) ? bq : (z == 1) ? bk : bv;
  int bt = blockIdx.x;               // 0..65; 33 i-tiles per batch
  int bg2 = bt / 33;                 // batch b
  int bm = (bt - bg2 * 33) * 64;     // i-tile base within batch
  int bn = blockIdx.y * 128;
  size_t rowbase = (size_t)bg2 * S_;

  int ar = tid >> 2, acq = (tid & 3) * 16;          // A: 64 rows x 64 cols
  int ai = bm + ar; if (ai >= S_) ai = S_ - 1;
  const ushort_t* ap = xb + (rowbase + ai) * E_ + acq;
  int br = tid >> 1, bcq = (tid & 1) * 32;          // B: 128 rows x 64 cols
  const ushort_t* bp = Wt + (size_t)(bn + br) * E_ + bcq;

  const f32x4 fz = {0.f, 0.f, 0.f, 0.f};
  f32x4 acc[2][4];
#pragma unroll
  for (int mt = 0; mt < 2; ++mt)
#pragma unroll
    for (int nt = 0; nt < 4; ++nt) acc[mt][nt] = fz;

  int4 pa0 = *(const int4*)ap, pa1 = *(const int4*)(ap + 8);
  int4 pb0 = *(const int4*)bp,        pb1 = *(const int4*)(bp + 8);
  int4 pb2 = *(const int4*)(bp + 16), pb3 = *(const int4*)(bp + 24);

  for (int k0 = 0; k0 < E_; k0 += 64) {
    __syncthreads();
    int kn = (k0 + 64 < E_) ? (k0 + 64) : k0;
    int4 na0 = *(const int4*)(ap + kn), na1 = *(const int4*)(ap + kn + 8);
    int4 nb0 = *(const int4*)(bp + kn),      nb1 = *(const int4*)(bp + kn + 8);
    int4 nb2 = *(const int4*)(bp + kn + 16), nb3 = *(const int4*)(bp + kn + 24);
    *(int4*)&As[ar][acq] = pa0; *(int4*)&As[ar][acq + 8] = pa1;
    *(int4*)&Bs[br][bcq] = pb0;      *(int4*)&Bs[br][bcq + 8] = pb1;
    *(int4*)&Bs[br][bcq + 16] = pb2; *(int4*)&Bs[br][bcq + 24] = pb3;
    __syncthreads();
    bf16x8 a[2][2], bfr[4][2];
#pragma unroll
    for (int mt = 0; mt < 2; ++mt) {
      a[mt][0] = *(const bf16x8*)&As[wm + mt * 16 + l15][quad * 8];
      a[mt][1] = *(const bf16x8*)&As[wm + mt * 16 + l15][32 + quad * 8];
    }
#pragma unroll
    for (int nt = 0; nt < 4; ++nt) {
      bfr[nt][0] = *(const bf16x8*)&Bs[wn + nt * 16 + l15][quad * 8];
      bfr[nt][1] = *(const bf16x8*)&Bs[wn + nt * 16 + l15][32 + quad * 8];
    }
    __builtin_amdgcn_s_setprio(1);
#pragma unroll
    for (int mt = 0; mt < 2; ++mt)
#pragma unroll
      for (int nt = 0; nt < 4; ++nt) {
        acc[mt][nt] = MFMA16(a[mt][0], bfr[nt][0], acc[mt][nt]);
        acc[mt][nt] = MFMA16(a[mt][1], bfr[nt][1], acc[mt][nt]);
      }
    __builtin_amdgcn_s_setprio(0);
    pa0 = na0; pa1 = na1; pb0 = nb0; pb1 = nb1; pb2 = nb2; pb3 = nb3;
  }

  float bb[4];
#pragma unroll
  for (int nt = 0; nt < 4; ++nt) bb[nt] = bias[bn + wn + nt * 16 + l15];

  if (z < 2) {
    ushort_t* C = qkb + (size_t)z * MROWS * E_;
#pragma unroll
    for (int mt = 0; mt < 2; ++mt)
#pragma unroll
      for (int nt = 0; nt < 4; ++nt)
#pragma unroll
        for (int r = 0; r < 4; ++r) {
          int i = bm + wm + mt * 16 + quad * 4 + r;
          if (i < S_)
            C[(rowbase + i) * E_ + bn + wn + nt * 16 + l15] = f2bf(acc[mt][nt][r] + bb[nt]);
        }
    // fused gate partial dots
    const float* wgp = wg + (size_t)z * E_;
    float wv[4];
#pragma unroll
    for (int nt = 0; nt < 4; ++nt) wv[nt] = wgp[bn + wn + nt * 16 + l15];
    float* gp = gacc + (size_t)z * GBUFN;
#pragma unroll
    for (int mt = 0; mt < 2; ++mt)
#pragma unroll
      for (int r = 0; r < 4; ++r) {
        float s = 0.f;
#pragma unroll
        for (int nt = 0; nt < 4; ++nt) s = fmaf(acc[mt][nt][r] + bb[nt], wv[nt], s);
        s += __shfl_xor(s, 1, 16); s += __shfl_xor(s, 2, 16);
        s += __shfl_xor(s, 4, 16); s += __shfl_xor(s, 8, 16);
        int i = bm + wm + mt * 16 + quad * 4 + r;
        if (l15 == 0 && i < S_) atomicAdd(&gp[rowbase + i], s);
      }
  } else {
    // v: LDS transpose (2-way conflicts = free) then coalesced aligned int4
    ushort_t* lt = &Bs[0][0];                    // 64d x 72i tile
    int ti = tid >> 2, tc = (tid & 3) * 16;
#pragma unroll
    for (int hh = 0; hh < 2; ++hh) {
      __syncthreads();
      if ((w >> 1) == hh) {
#pragma unroll
        for (int mt = 0; mt < 2; ++mt)
#pragma unroll
          for (int nt = 0; nt < 4; ++nt) {
            int d = nt * 16 + l15;
#pragma unroll
            for (int r = 0; r < 4; ++r) {
              int il = wm + mt * 16 + quad * 4 + r;
              lt[d * 72 + il] = f2bf(acc[mt][nt][r] + bb[nt]);
            }
          }
      }
      __syncthreads();
      int hg = (bn >> 6) + hh;
      union { int4 q[2]; ushort_t u[16]; } tv;
      tv.q[0] = *(const int4*)&lt[ti * 72 + tc];
      tv.q[1] = *(const int4*)&lt[ti * 72 + tc + 8];
      size_t vrow = ((size_t)(bg2 * H_ + hg) * 64 + ti) * SP_;
#pragma unroll
      for (int c8 = 0; c8 < 2; ++c8) {
        int i2 = bm + tc + c8 * 8;
        if (i2 + 7 < S_) {
          *(int4*)&vT[vrow + i2] = tv.q[c8];
        } else {
#pragma unroll
          for (int e = 0; e < 8; ++e)
            if (i2 + e < S_) vT[vrow + i2 + e] = tv.u[c8 * 8 + e];
        }
      }
    }
  }
}

// ---------------------------------------------------------------------------
// MFMA flash attention, S^T form, fixed-reference softmax, thirds split.
// R0 structure (1584 blocks x 256 thr, 5 blocks/CU, plain fp32 partial
// stores — proven 45.8 µs) + setprio around MFMA clusters.
// ---------------------------------------------------------------------------
__global__ __launch_bounds__(256) void attn_kernel(
    const ushort_t* __restrict__ qb, const ushort_t* __restrict__ kb,
    const ushort_t* __restrict__ vT, const float* __restrict__ gq_raw,
    const float* __restrict__ gk_raw, const float* __restrict__ bgate,
    float* __restrict__ Opart, float* __restrict__ Lpart)
{
  __shared__ __align__(16) ushort_t Ks[64][72];    // [j][d]
  __shared__ __align__(16) ushort_t Vt[64][72];    // [d][j]
  __shared__ __align__(16) ushort_t Ps[4][16][72]; // per-wave P [i][j]
  __shared__ float gbs[704];

  int tid = threadIdx.x;
  int lane = tid & 63, w = tid >> 6;
  int l15 = lane & 15, quad = lane >> 4;

  // middle-out q-tile order; 48 blocks (16 bh x 3 thirds) per qt
  int sub = blockIdx.x % 48;
  int qidx = blockIdx.x / 48;
  int off = (qidx + 1) >> 1;
  int qt = 16 + ((qidx & 1) ? -off : off);          // 0..32
  int bh = sub & 15, third = sub >> 4;
  int h = bh & 7, b = bh >> 3;
  int i0 = qt * 64;
  const float LOG2E = 1.44269504f;
  const float coef2 = (-0.5f / (512.f * 512.f)) * LOG2E;
  const float QSC = 0.125f * LOG2E;

  // per-thread q-row
  int i = i0 + w * 16 + l15;
  int ic = (i < S_) ? i : S_ - 1;
  bf16x8 qf0 = *(const bf16x8*)&qb[((size_t)(b * S_ + ic)) * E_ + h * 64 + quad * 8];
  bf16x8 qf1 = *(const bf16x8*)&qb[((size_t)(b * S_ + ic)) * E_ + h * 64 + 32 + quad * 8];
#pragma unroll
  for (int e = 0; e < 8; ++e) {                     // fold D^-0.5 * log2e into Q
    qf0[e] = (short)f2bf(bf2f((ushort_t)qf0[e]) * QSC);
    qf1[e] = (short)f2bf(bf2f((ushort_t)qf1[e]) * QSC);
  }
  float av = __expf(-(gq_raw[b * S_ + ic] + bgate[0]));
  float fdi = (i < S_) ? (float)i : -1e5f;

  int jlo = i0 - WIN_; if (jlo < 0) jlo = 0;
  int jt_lo = jlo >> 6;
  int jhi = i0 + 63 + WIN_; if (jhi > S_ - 1) jhi = S_ - 1;
  int jt_hi = jhi >> 6;
  int L = jt_hi - jt_lo + 1;                        // 17..33
  int n0 = (L + 2) / 3, n1 = (L + 1) / 3;
  int myLo = jt_lo + ((third == 0) ? 0 : (third == 1) ? n0 : n0 + n1);
  int cnt = (third == 0) ? n0 : (third == 1) ? n1 : L - n0 - n1;
  int myHi = myLo + cnt - 1;
  int jbase = myLo << 6;
  int nwin = cnt << 6;                              // <= 704

  for (int tt = tid; tt < nwin; tt += 256) {
    int j = jbase + tt; int jc = (j < S_) ? j : S_ - 1;
    gbs[tt] = __expf(-gk_raw[b * S_ + jc]);
  }

  // staging maps: K rows=j, V^T rows=d; both 64x64, 2 int4 per thread
  int srow = tid >> 2, scol = (tid & 3) * 16;
  const ushort_t* kb_base = kb + (size_t)b * S_ * E_ + h * 64 + scol;
  const ushort_t* vb_base = vT + ((size_t)(b * H_ + h) * 64 + srow) * SP_ + scol;

  int4 ka0, ka1, va0, va1;
  {
    int jc0 = jbase + srow; if (jc0 > S_ - 1) jc0 = S_ - 1;
    const int4* kp = (const int4*)(kb_base + (size_t)jc0 * E_);
    ka0 = kp[0]; ka1 = kp[1];
    const int4* vp = (const int4*)(vb_base + jbase);
    va0 = vp[0]; va1 = vp[1];
  }

  const f32x4 fz = {0.f, 0.f, 0.f, 0.f};
  f32x4 Ov[4] = {fz, fz, fz, fz};
  float l_run = 0.f;

  for (int jt = myLo; jt <= myHi; ++jt) {
    int j0 = jt << 6;
    __syncthreads();
    int jn = (jt < myHi) ? ((jt + 1) << 6) : j0;
    int jcn = jn + srow; if (jcn > S_ - 1) jcn = S_ - 1;
    const int4* kp = (const int4*)(kb_base + (size_t)jcn * E_);
    int4 nk0 = kp[0], nk1 = kp[1];
    const int4* vp = (const int4*)(vb_base + jn);
    int4 nv0 = vp[0], nv1 = vp[1];
    *(int4*)&Ks[srow][scol] = ka0; *(int4*)&Ks[srow][scol + 8] = ka1;
    *(int4*)&Vt[srow][scol] = va0; *(int4*)&Vt[srow][scol + 8] = va1;
    __syncthreads();

    // S^T = K . Q^T : lane holds one q-row (i=l15), 16 j's
    f32x4 st[4];
    __builtin_amdgcn_s_setprio(1);
#pragma unroll
    for (int nt = 0; nt < 4; ++nt) {
      bf16x8 kf0 = *(const bf16x8*)&Ks[nt * 16 + l15][quad * 8];
      bf16x8 kf1 = *(const bf16x8*)&Ks[nt * 16 + l15][32 + quad * 8];
      f32x4 s = MFMA16(kf0, qf0, fz);
      st[nt] = MFMA16(kf1, qf1, s);
    }
    __builtin_amdgcn_s_setprio(0);

    bool full = ((j0 + 63 - i0) <= WIN_) && ((i0 + 63 - j0) <= WIN_)
                && (j0 + 63 < S_) && (i0 + 63 < S_);
    float ps = 0.f;
    float fq = fdi - (float)(j0 + quad * 4);
    if (full) {
#pragma unroll
      for (int nt = 0; nt < 4; ++nt) {
        f32x4 g4 = *(const f32x4*)&gbs[(j0 - jbase) + nt * 16 + quad * 4];
#pragma unroll
        for (int r = 0; r < 4; ++r) {
          float f = fq - (float)(nt * 16 + r);
          float gate = __builtin_amdgcn_rcpf(fmaf(av, g4[r], 1.f));
          float p = __builtin_amdgcn_exp2f(fmaf(f * f, coef2, st[nt][r]) * gate);
          st[nt][r] = p; ps += p;
        }
      }
    } else {
#pragma unroll
      for (int nt = 0; nt < 4; ++nt) {
        f32x4 g4 = *(const f32x4*)&gbs[(j0 - jbase) + nt * 16 + quad * 4];
#pragma unroll
        for (int r = 0; r < 4; ++r) {
          int j = j0 + nt * 16 + quad * 4 + r;
          float fj = (j < S_) ? (float)j : 1e5f;
          float f = fdi - fj;
          float gate = __builtin_amdgcn_rcpf(fmaf(av, g4[r], 1.f));
          float t = fmaf(f * f, coef2, st[nt][r]) * gate;
          t = (__builtin_fabsf(f) <= 1024.f) ? t : -1e30f;
          float p = __builtin_amdgcn_exp2f(t);
          st[nt][r] = p; ps += p;
        }
      }
    }
    ps += __shfl_xor(ps, 16);
    ps += __shfl_xor(ps, 32);
    l_run += ps;

#pragma unroll
    for (int nt = 0; nt < 4; ++nt) {
      uint2 pk;
      pk.x = (unsigned int)f2bf(st[nt][0]) | ((unsigned int)f2bf(st[nt][1]) << 16);
      pk.y = (unsigned int)f2bf(st[nt][2]) | ((unsigned int)f2bf(st[nt][3]) << 16);
      *(uint2*)&Ps[w][l15][nt * 16 + quad * 4] = pk;
    }
    bf16x8 p0 = *(const bf16x8*)&Ps[w][l15][quad * 8];
    bf16x8 p1 = *(const bf16x8*)&Ps[w][l15][32 + quad * 8];
    __builtin_amdgcn_s_setprio(1);
#pragma unroll
    for (int nt = 0; nt < 4; ++nt) {
      bf16x8 v0 = *(const bf16x8*)&Vt[nt * 16 + l15][quad * 8];
      bf16x8 v1 = *(const bf16x8*)&Vt[nt * 16 + l15][32 + quad * 8];
      Ov[nt] = MFMA16(p0, v0, Ov[nt]);
      Ov[nt] = MFMA16(p1, v1, Ov[nt]);
    }
    __builtin_amdgcn_s_setprio(0);
    ka0 = nk0; ka1 = nk1; va0 = nv0; va1 = nv1;
  }

  // store unnormalized partials (fp32)
  if (lane < 16) {
    int irow = i0 + w * 16 + lane;
    if (irow < S_)
      Lpart[(size_t)third * BHS_ + (size_t)(b * H_ + h) * S_ + irow] = l_run;
  }
#pragma unroll
  for (int r = 0; r < 4; ++r) {
    int irow = i0 + w * 16 + quad * 4 + r;
    if (irow < S_) {
      size_t base = ((size_t)third * BHS_ + (size_t)(b * H_ + h) * S_ + irow) * 64;
#pragma unroll
      for (int nt = 0; nt < 4; ++nt)
        Opart[base + nt * 16 + l15] = Ov[nt][r];
    }
  }
}

// ---------------------------------------------------------------------------
// Combine thirds: o = (O1+O2+O3)/(l1+l2+l3); emit hi/lo bf16, row-major.
// ---------------------------------------------------------------------------
__global__ __launch_bounds__(256) void combine_kernel(
    const float* __restrict__ Opart, const float* __restrict__ Lpart,
    ushort_t* __restrict__ ahi, ushort_t* __restrict__ alo)
{
  int tid = threadIdx.x;
  int gi = blockIdx.x * 16 + (tid >> 4);            // [0, 32784)
  int d4 = tid & 15;
  int b = gi / (H_ * S_);
  int rem = gi - b * (H_ * S_);
  int h = rem / S_;
  int i = rem - h * S_;
  size_t p0 = (size_t)(b * H_ + h) * S_ + i;
  float l = Lpart[p0] + Lpart[p0 + (size_t)BHS_] + Lpart[p0 + 2 * (size_t)BHS_];
  float inv = 1.f / l;
  const float* op = Opart + p0 * 64 + d4 * 4;
  float4 o1 = *(const float4*)op;
  float4 o2 = *(const float4*)(op + (size_t)BHS_ * 64);
  float4 o3 = *(const float4*)(op + 2 * (size_t)BHS_ * 64);
  float o[4] = {(o1.x + o2.x + o3.x) * inv, (o1.y + o2.y + o3.y) * inv,
                (o1.z + o2.z + o3.z) * inv, (o1.w + o2.w + o3.w) * inv};
  ushort4 hi, lo;
  hi.x = f2bf(o[0]); lo.x = f2bf(o[0] - bf2f(hi.x));
  hi.y = f2bf(o[1]); lo.y = f2bf(o[1] - bf2f(hi.y));
  hi.z = f2bf(o[2]); lo.z = f2bf(o[2] - bf2f(hi.z));
  hi.w = f2bf(o[3]); lo.w = f2bf(o[3] - bf2f(hi.w));
  size_t oidx = ((size_t)b * S_ + i) * E_ + h * 64 + d4 * 4;
  *(ushort4*)&ahi[oidx] = hi;
  *(ushort4*)&alo[oidx] = lo;
}

// ---------------------------------------------------------------------------
// Output projection, 64x64 tile, 2x2 waves (32x32 each), BK=64 (8 K-steps),
// 2-term split: C = (Ahi + Alo) @ Whi + bias (fp32 out). Grid (65,8) = 520
// blocks (2 blocks/CU), reg-prefetch.
// ---------------------------------------------------------------------------
__global__ __launch_bounds__(256) void gemm_out_kernel(
    const ushort_t* __restrict__ Ahi, const ushort_t* __restrict__ Alo,
    const ushort_t* __restrict__ Whi, const float* __restrict__ bias,
    float* __restrict__ C)
{
  __shared__ __align__(16) ushort_t AsH[64][72];
  __shared__ __align__(16) ushort_t AsL[64][72];
  __shared__ __align__(16) ushort_t BsW[64][72];
  int tid = threadIdx.x;
  int lane = tid & 63, w = tid >> 6;
  int l15 = lane & 15, quad = lane >> 4;
  int wm = (w & 1) * 32, wn = (w >> 1) * 32;
  int bm = blockIdx.x * 64, bn = blockIdx.y * 64;

  int sr = tid >> 2, sc = (tid & 3) * 16;           // 64 rows x 64 cols
  int am = bm + sr; if (am >= MROWS) am = MROWS - 1;
  const ushort_t* ahp = Ahi + (size_t)am * E_ + sc;
  const ushort_t* alp = Alo + (size_t)am * E_ + sc;
  const ushort_t* bp = Whi + (size_t)(bn + sr) * E_ + sc;

  const f32x4 fz = {0.f, 0.f, 0.f, 0.f};
  f32x4 acc[2][2];
#pragma unroll
  for (int mt = 0; mt < 2; ++mt)
#pragma unroll
    for (int nt = 0; nt < 2; ++nt) acc[mt][nt] = fz;

  int4 ph0 = *(const int4*)ahp, ph1 = *(const int4*)(ahp + 8);
  int4 pl0 = *(const int4*)alp, pl1 = *(const int4*)(alp + 8);
  int4 pb0 = *(const int4*)bp,  pb1 = *(const int4*)(bp + 8);

  for (int k0 = 0; k0 < E_; k0 += 64) {
    __syncthreads();
    int kn = (k0 + 64 < E_) ? (k0 + 64) : k0;
    int4 nh0 = *(const int4*)(ahp + kn), nh1 = *(const int4*)(ahp + kn + 8);
    int4 nl0 = *(const int4*)(alp + kn), nl1 = *(const int4*)(alp + kn + 8);
    int4 nb0 = *(const int4*)(bp + kn),  nb1 = *(const int4*)(bp + kn + 8);
    *(int4*)&AsH[sr][sc] = ph0; *(int4*)&AsH[sr][sc + 8] = ph1;
    *(int4*)&AsL[sr][sc] = pl0; *(int4*)&AsL[sr][sc + 8] = pl1;
    *(int4*)&BsW[sr][sc] = pb0; *(int4*)&BsW[sr][sc + 8] = pb1;
    __syncthreads();
    bf16x8 ah[2][2], al[2][2], bw[2][2];
#pragma unroll
    for (int mt = 0; mt < 2; ++mt) {
      ah[mt][0] = *(const bf16x8*)&AsH[wm + mt * 16 + l15][quad * 8];
      ah[mt][1] = *(const bf16x8*)&AsH[wm + mt * 16 + l15][32 + quad * 8];
      al[mt][0] = *(const bf16x8*)&AsL[wm + mt * 16 + l15][quad * 8];
      al[mt][1] = *(const bf16x8*)&AsL[wm + mt * 16 + l15][32 + quad * 8];
    }
#pragma unroll
    for (int nt = 0; nt < 2; ++nt) {
      bw[nt][0] = *(const bf16x8*)&BsW[wn + nt * 16 + l15][quad * 8];
      bw[nt][1] = *(const bf16x8*)&BsW[wn + nt * 16 + l15][32 + quad * 8];
    }
    __builtin_amdgcn_s_setprio(1);
#pragma unroll
    for (int mt = 0; mt < 2; ++mt)
#pragma unroll
      for (int nt = 0; nt < 2; ++nt) {
        acc[mt][nt] = MFMA16(ah[mt][0], bw[nt][0], acc[mt][nt]);
        acc[mt][nt] = MFMA16(al[mt][0], bw[nt][0], acc[mt][nt]);
        acc[mt][nt] = MFMA16(ah[mt][1], bw[nt][1], acc[mt][nt]);
        acc[mt][nt] = MFMA16(al[mt][1], bw[nt][1], acc[mt][nt]);
      }
    __builtin_amdgcn_s_setprio(0);
    ph0 = nh0; ph1 = nh1; pl0 = nl0; pl1 = nl1; pb0 = nb0; pb1 = nb1;
  }
#pragma unroll
  for (int nt = 0; nt < 2; ++nt) {
    float bb = bias[bn + wn + nt * 16 + l15];
#pragma unroll
    for (int mt = 0; mt < 2; ++mt)
#pragma unroll
      for (int r = 0; r < 4; ++r) {
        int m = bm + wm + mt * 16 + quad * 4 + r;
        if (m < MROWS)
          C[(size_t)m * E_ + bn + wn + nt * 16 + l15] = acc[mt][nt][r] + bb;
      }
  }
}

// ---------------------------------------------------------------------------
extern "C" void kernel_launch(void* const* d_in, const int* in_sizes, int n_in,
                              void* d_out, int out_size, void* d_ws, size_t ws_size,
                              hipStream_t stream) {
  const float* x  = (const float*)d_in[0];
  const float* Wq = (const float*)d_in[1];
  const float* bq = (const float*)d_in[2];
  const float* Wk = (const float*)d_in[3];
  const float* bk = (const float*)d_in[4];
  const float* Wv = (const float*)d_in[5];
  const float* bv = (const float*)d_in[6];
  const float* Wo = (const float*)d_in[7];
  const float* bo = (const float*)d_in[8];
  const float* wg = (const float*)d_in[9];
  const float* bg = (const float*)d_in[10];

  char* p = (char*)d_ws;
  ushort_t* Wt_all = (ushort_t*)p; p += (size_t)3 * E_ * E_ * 2;         // 1.57 MB
  ushort_t* WoHi   = (ushort_t*)p; p += (size_t)E_ * E_ * 2;             // 0.52 MB
  ushort_t* qkb    = (ushort_t*)p; p += (size_t)2 * MROWS * E_ * 2;      // 8.39 MB
  ushort_t* vT     = (ushort_t*)p; p += (size_t)B_ * H_ * 64 * SP_ * 2;  // 4.46 MB
  float*    gacc   = (float*)p;    p += (size_t)2 * GBUFN * 4;           // 33 KB
  float*    Opart  = (float*)p;    p += (size_t)3 * BHS_ * 64 * 4;       // 25.2 MB
  float*    Lpart  = (float*)p;    p += (size_t)3 * BHS_ * 4;            // 0.39 MB
  // xb aliases Opart: xb is dead after qkv; Opart written only in attn.
  ushort_t* xb     = (ushort_t*)Opart;
  // aHi/aLo alias qkb: q/k are dead once attn completes (stream-ordered).
  ushort_t* aHi    = qkb;
  ushort_t* aLo    = qkb + (size_t)MROWS * E_;

  hipLaunchKernelGGL(convert_all_kernel, dim3(3073), dim3(256), 0, stream,
                     x, Wq, Wk, Wv, Wo, xb, Wt_all, WoHi, gacc);
  hipLaunchKernelGGL(gemm_qkv_kernel, dim3(66, 4, 3), dim3(256), 0, stream,
                     xb, Wt_all, bq, bk, bv, wg, qkb, vT, gacc);
  hipLaunchKernelGGL(attn_kernel, dim3(33 * 48), dim3(256), 0, stream,
                     qkb, qkb + (size_t)MROWS * E_, vT, gacc, gacc + GBUFN, bg,
                     Opart, Lpart);
  hipLaunchKernelGGL(combine_kernel, dim3(2049), dim3(256), 0, stream,
                     Opart, Lpart, aHi, aLo);
  hipLaunchKernelGGL(gemm_out_kernel, dim3(65, 8), dim3(256), 0, stream,
                     aHi, aLo, WoHi, bo, (float*)d_out);
}

// Round 4
// 159.904 us; speedup vs baseline: 1.0598x; 1.0185x over previous
//
#include <hip/hip_runtime.h>
#include <cstdint>
#include <cstddef>

#define B_ 2
#define S_ 2049
#define E_ 512
#define H_ 8
#define WIN_ 1024
#define MROWS (B_*S_)     // 4098
#define SP_ 2176          // padded seq for vT cols
#define GBUFN 4104
#define BHS_ (B_*H_*S_)   // 32784

typedef unsigned short ushort_t;
typedef __attribute__((ext_vector_type(8))) short bf16x8;   // 8 bf16 (4 VGPRs)
typedef __attribute__((ext_vector_type(4))) float f32x4;

#define MFMA16(a,b,c) __builtin_amdgcn_mfma_f32_16x16x32_bf16(a,b,c,0,0,0)

__device__ __forceinline__ ushort_t f2bf(float f) {          // RNE fp32->bf16
  unsigned int u = __float_as_uint(f);
  u += 0x7fffu + ((u >> 16) & 1u);
  return (ushort_t)(u >> 16);
}
__device__ __forceinline__ float bf2f(ushort_t h) {
  return __uint_as_float(((unsigned int)h) << 16);
}

// ---------------------------------------------------------------------------
// One launch: blocks [0,2049) convert x fp32->bf16 (coalesced float4);
// blocks [2049,3073): W [k][n] -> Wt [n][k] bf16 (z<3) / WoHi (z==3),
// z==3 blocks also zero the gate accumulators.
// ---------------------------------------------------------------------------
__global__ __launch_bounds__(256) void convert_all_kernel(
    const float* __restrict__ x, const float* __restrict__ W0,
    const float* __restrict__ W1, const float* __restrict__ W2,
    const float* __restrict__ W3, ushort_t* __restrict__ xb,
    ushort_t* __restrict__ Wt_all, ushort_t* __restrict__ WoHi,
    float* __restrict__ gacc)
{
  __shared__ float tile[32][33];
  int bid = blockIdx.x;
  if (bid < 2049) {
    int idx = bid * 256 + threadIdx.x;               // exactly MROWS*E_/4
    float4 v = ((const float4*)x)[idx];
    ushort4 o;
    o.x = f2bf(v.x); o.y = f2bf(v.y); o.z = f2bf(v.z); o.w = f2bf(v.w);
    ((ushort4*)xb)[idx] = o;
    return;
  }
  int wid = bid - 2049;
  int z = wid >> 8, rem = wid & 255;
  if (z == 3) {
    int gz = rem * 256 + threadIdx.x;
    if (gz < 2 * GBUFN) gacc[gz] = 0.f;
  }
  const float* W = (z == 0) ? W0 : (z == 1) ? W1 : (z == 2) ? W2 : W3;
  int k0 = (rem >> 4) * 32, n0 = (rem & 15) * 32;
  int r = threadIdx.x >> 5, c = threadIdx.x & 31;
#pragma unroll
  for (int i = 0; i < 4; ++i) {
    int rr = r + i * 8;
    tile[rr][c] = W[(size_t)(k0 + rr) * E_ + n0 + c];
  }
  __syncthreads();
#pragma unroll
  for (int i = 0; i < 4; ++i) {
    int rr = r + i * 8;
    float v = tile[c][rr];                       // = W[k0+c][n0+rr]
    size_t dst = (size_t)(n0 + rr) * E_ + k0 + c;
    if (z < 3) Wt_all[(size_t)z * E_ * E_ + dst] = f2bf(v);
    else       WoHi[dst] = f2bf(v);
  }
}

// ---------------------------------------------------------------------------
// QKV projection, 64x128 tile, 2x2 waves (32x64 each), BK=64 (8 K-steps),
// reg-prefetch, bf16 xb. Per-b m-tiling (grid.x=66).
// z<2: row-major bf16 + fused gate partial dots. z==2: LDS-transpose -> vT.
// ---------------------------------------------------------------------------
__global__ __launch_bounds__(256) void gemm_qkv_kernel(
    const ushort_t* __restrict__ xb, const ushort_t* __restrict__ Wt_all,
    const float* __restrict__ bq, const float* __restrict__ bk,
    const float* __restrict__ bv, const float* __restrict__ wg,
    ushort_t* __restrict__ qkb, ushort_t* __restrict__ vT,
    float* __restrict__ gacc)
{
  __shared__ __align__(16) ushort_t As[64][72];
  __shared__ __align__(16) ushort_t Bs[128][72];
  int tid = threadIdx.x;
  int lane = tid & 63, w = tid >> 6;
  int l15 = lane & 15, quad = lane >> 4;
  int wm = (w & 1) * 32, wn = (w >> 1) * 64;
  int z = blockIdx.z;
  const ushort_t* Wt = Wt_all + (size_t)z * E_ * E_;
  const float* bias = (z == 0) ? bq : (z == 1) ? bk : bv;
  int bt = blockIdx.x;               // 0..65; 33 i-tiles per batch
  int bg2 = bt / 33;                 // batch b
  int bm = (bt - bg2 * 33) * 64;     // i-tile base within batch
  int bn = blockIdx.y * 128;
  size_t rowbase = (size_t)bg2 * S_;

  int ar = tid >> 2, acq = (tid & 3) * 16;          // A: 64 rows x 64 cols
  int ai = bm + ar; if (ai >= S_) ai = S_ - 1;
  const ushort_t* ap = xb + (rowbase + ai) * E_ + acq;
  int br = tid >> 1, bcq = (tid & 1) * 32;          // B: 128 rows x 64 cols
  const ushort_t* bp = Wt + (size_t)(bn + br) * E_ + bcq;

  const f32x4 fz = {0.f, 0.f, 0.f, 0.f};
  f32x4 acc[2][4];
#pragma unroll
  for (int mt = 0; mt < 2; ++mt)
#pragma unroll
    for (int nt = 0; nt < 4; ++nt) acc[mt][nt] = fz;

  int4 pa0 = *(const int4*)ap, pa1 = *(const int4*)(ap + 8);
  int4 pb0 = *(const int4*)bp,        pb1 = *(const int4*)(bp + 8);
  int4 pb2 = *(const int4*)(bp + 16), pb3 = *(const int4*)(bp + 24);

  for (int k0 = 0; k0 < E_; k0 += 64) {
    __syncthreads();
    int kn = (k0 + 64 < E_) ? (k0 + 64) : k0;
    int4 na0 = *(const int4*)(ap + kn), na1 = *(const int4*)(ap + kn + 8);
    int4 nb0 = *(const int4*)(bp + kn),      nb1 = *(const int4*)(bp + kn + 8);
    int4 nb2 = *(const int4*)(bp + kn + 16), nb3 = *(const int4*)(bp + kn + 24);
    *(int4*)&As[ar][acq] = pa0; *(int4*)&As[ar][acq + 8] = pa1;
    *(int4*)&Bs[br][bcq] = pb0;      *(int4*)&Bs[br][bcq + 8] = pb1;
    *(int4*)&Bs[br][bcq + 16] = pb2; *(int4*)&Bs[br][bcq + 24] = pb3;
    __syncthreads();
    bf16x8 a[2][2], bfr[4][2];
#pragma unroll
    for (int mt = 0; mt < 2; ++mt) {
      a[mt][0] = *(const bf16x8*)&As[wm + mt * 16 + l15][quad * 8];
      a[mt][1] = *(const bf16x8*)&As[wm + mt * 16 + l15][32 + quad * 8];
    }
#pragma unroll
    for (int nt = 0; nt < 4; ++nt) {
      bfr[nt][0] = *(const bf16x8*)&Bs[wn + nt * 16 + l15][quad * 8];
      bfr[nt][1] = *(const bf16x8*)&Bs[wn + nt * 16 + l15][32 + quad * 8];
    }
    __builtin_amdgcn_s_setprio(1);
#pragma unroll
    for (int mt = 0; mt < 2; ++mt)
#pragma unroll
      for (int nt = 0; nt < 4; ++nt) {
        acc[mt][nt] = MFMA16(a[mt][0], bfr[nt][0], acc[mt][nt]);
        acc[mt][nt] = MFMA16(a[mt][1], bfr[nt][1], acc[mt][nt]);
      }
    __builtin_amdgcn_s_setprio(0);
    pa0 = na0; pa1 = na1; pb0 = nb0; pb1 = nb1; pb2 = nb2; pb3 = nb3;
  }

  float bb[4];
#pragma unroll
  for (int nt = 0; nt < 4; ++nt) bb[nt] = bias[bn + wn + nt * 16 + l15];

  if (z < 2) {
    ushort_t* C = qkb + (size_t)z * MROWS * E_;
#pragma unroll
    for (int mt = 0; mt < 2; ++mt)
#pragma unroll
      for (int nt = 0; nt < 4; ++nt)
#pragma unroll
        for (int r = 0; r < 4; ++r) {
          int i = bm + wm + mt * 16 + quad * 4 + r;
          if (i < S_)
            C[(rowbase + i) * E_ + bn + wn + nt * 16 + l15] = f2bf(acc[mt][nt][r] + bb[nt]);
        }
    // fused gate partial dots
    const float* wgp = wg + (size_t)z * E_;
    float wv[4];
#pragma unroll
    for (int nt = 0; nt < 4; ++nt) wv[nt] = wgp[bn + wn + nt * 16 + l15];
    float* gp = gacc + (size_t)z * GBUFN;
#pragma unroll
    for (int mt = 0; mt < 2; ++mt)
#pragma unroll
      for (int r = 0; r < 4; ++r) {
        float s = 0.f;
#pragma unroll
        for (int nt = 0; nt < 4; ++nt) s = fmaf(acc[mt][nt][r] + bb[nt], wv[nt], s);
        s += __shfl_xor(s, 1, 16); s += __shfl_xor(s, 2, 16);
        s += __shfl_xor(s, 4, 16); s += __shfl_xor(s, 8, 16);
        int i = bm + wm + mt * 16 + quad * 4 + r;
        if (l15 == 0 && i < S_) atomicAdd(&gp[rowbase + i], s);
      }
  } else {
    // v: LDS transpose (2-way conflicts = free) then coalesced aligned int4
    ushort_t* lt = &Bs[0][0];                    // 64d x 72i tile
    int ti = tid >> 2, tc = (tid & 3) * 16;
#pragma unroll
    for (int hh = 0; hh < 2; ++hh) {
      __syncthreads();
      if ((w >> 1) == hh) {
#pragma unroll
        for (int mt = 0; mt < 2; ++mt)
#pragma unroll
          for (int nt = 0; nt < 4; ++nt) {
            int d = nt * 16 + l15;
#pragma unroll
            for (int r = 0; r < 4; ++r) {
              int il = wm + mt * 16 + quad * 4 + r;
              lt[d * 72 + il] = f2bf(acc[mt][nt][r] + bb[nt]);
            }
          }
      }
      __syncthreads();
      int hg = (bn >> 6) + hh;
      union { int4 q[2]; ushort_t u[16]; } tv;
      tv.q[0] = *(const int4*)&lt[ti * 72 + tc];
      tv.q[1] = *(const int4*)&lt[ti * 72 + tc + 8];
      size_t vrow = ((size_t)(bg2 * H_ + hg) * 64 + ti) * SP_;
#pragma unroll
      for (int c8 = 0; c8 < 2; ++c8) {
        int i2 = bm + tc + c8 * 8;
        if (i2 + 7 < S_) {
          *(int4*)&vT[vrow + i2] = tv.q[c8];
        } else {
#pragma unroll
          for (int e = 0; e < 8; ++e)
            if (i2 + e < S_) vT[vrow + i2 + e] = tv.u[c8 * 8 + e];
        }
      }
    }
  }
}

// ---------------------------------------------------------------------------
// MFMA flash attention, S^T form, fixed-reference softmax, thirds split.
// R3 structure (1584 blocks x 256 thr, 5 blocks/CU) with three VALU/LDS
// optimizations:
//  - T2 XOR-swizzle on Ks/Vt/Ps ([64][64] tiles, slot ^= row&7) — targets
//    the 4.6M SQ_LDS_BANK_CONFLICT cycles (~17% of attn time).
//  - T12 v_cvt_pk_bf16_f32 for the P->bf16 pack (was ~60 scalar VALU/tile).
//  - l-row-sum via MFMA with a ones B-operand (P·1) on the idle MFMA pipe,
//    replacing 16 VALU adds + 2 shuffles; also makes l consistent with the
//    rounded-bf16 P used in PV.
// ---------------------------------------------------------------------------
__device__ __forceinline__ int swz(int row, int slot) {   // ushort idx in [64][64] tile
  return row * 64 + ((slot ^ (row & 7)) << 3);
}

__global__ __launch_bounds__(256) void attn_kernel(
    const ushort_t* __restrict__ qb, const ushort_t* __restrict__ kb,
    const ushort_t* __restrict__ vT, const float* __restrict__ gq_raw,
    const float* __restrict__ gk_raw, const float* __restrict__ bgate,
    float* __restrict__ Opart, float* __restrict__ Lpart)
{
  __shared__ __align__(16) ushort_t Ks[64 * 64];   // [j][d] swizzled
  __shared__ __align__(16) ushort_t Vt[64 * 64];   // [d][j] swizzled
  __shared__ __align__(16) ushort_t Ps[4 * 16 * 64]; // per-wave P [i][j] swizzled
  __shared__ float gbs[704];

  int tid = threadIdx.x;
  int lane = tid & 63, w = tid >> 6;
  int l15 = lane & 15, quad = lane >> 4;

  // middle-out q-tile order; 48 blocks (16 bh x 3 thirds) per qt
  int sub = blockIdx.x % 48;
  int qidx = blockIdx.x / 48;
  int off = (qidx + 1) >> 1;
  int qt = 16 + ((qidx & 1) ? -off : off);          // 0..32
  int bh = sub & 15, third = sub >> 4;
  int h = bh & 7, b = bh >> 3;
  int i0 = qt * 64;
  const float LOG2E = 1.44269504f;
  const float coef2 = (-0.5f / (512.f * 512.f)) * LOG2E;
  const float QSC = 0.125f * LOG2E;

  // per-thread q-row
  int i = i0 + w * 16 + l15;
  int ic = (i < S_) ? i : S_ - 1;
  bf16x8 qf0 = *(const bf16x8*)&qb[((size_t)(b * S_ + ic)) * E_ + h * 64 + quad * 8];
  bf16x8 qf1 = *(const bf16x8*)&qb[((size_t)(b * S_ + ic)) * E_ + h * 64 + 32 + quad * 8];
#pragma unroll
  for (int e = 0; e < 8; ++e) {                     // fold D^-0.5 * log2e into Q
    qf0[e] = (short)f2bf(bf2f((ushort_t)qf0[e]) * QSC);
    qf1[e] = (short)f2bf(bf2f((ushort_t)qf1[e]) * QSC);
  }
  float av = __expf(-(gq_raw[b * S_ + ic] + bgate[0]));
  float fdi = (i < S_) ? (float)i : -1e5f;

  int jlo = i0 - WIN_; if (jlo < 0) jlo = 0;
  int jt_lo = jlo >> 6;
  int jhi = i0 + 63 + WIN_; if (jhi > S_ - 1) jhi = S_ - 1;
  int jt_hi = jhi >> 6;
  int L = jt_hi - jt_lo + 1;                        // 17..33
  int n0 = (L + 2) / 3, n1 = (L + 1) / 3;
  int myLo = jt_lo + ((third == 0) ? 0 : (third == 1) ? n0 : n0 + n1);
  int cnt = (third == 0) ? n0 : (third == 1) ? n1 : L - n0 - n1;
  int myHi = myLo + cnt - 1;
  int jbase = myLo << 6;
  int nwin = cnt << 6;                              // <= 704

  for (int tt = tid; tt < nwin; tt += 256) {
    int j = jbase + tt; int jc = (j < S_) ? j : S_ - 1;
    gbs[tt] = __expf(-gk_raw[b * S_ + jc]);
  }

  // staging maps: K rows=j, V^T rows=d; both 64x64, 2 int4 per thread.
  // LDS dest slots: row srow, slots 2c / 2c+1 (c = tid&3), XOR-swizzled.
  int srow = tid >> 2, sc4 = tid & 3;
  int scol = sc4 * 16;
  int wl0 = swz(srow, 2 * sc4), wl1 = swz(srow, 2 * sc4 + 1);
  const ushort_t* kb_base = kb + (size_t)b * S_ * E_ + h * 64 + scol;
  const ushort_t* vb_base = vT + ((size_t)(b * H_ + h) * 64 + srow) * SP_ + scol;

  int4 ka0, ka1, va0, va1;
  {
    int jc0 = jbase + srow; if (jc0 > S_ - 1) jc0 = S_ - 1;
    const int4* kp = (const int4*)(kb_base + (size_t)jc0 * E_);
    ka0 = kp[0]; ka1 = kp[1];
    const int4* vp = (const int4*)(vb_base + jbase);
    va0 = vp[0]; va1 = vp[1];
  }

  const f32x4 fz = {0.f, 0.f, 0.f, 0.f};
  f32x4 Ov[4] = {fz, fz, fz, fz};
  const bf16x8 ones = {16256, 16256, 16256, 16256, 16256, 16256, 16256, 16256};
  f32x4 Lv = fz;

  // per-wave P base and swizzled P slot addresses (loop-invariant)
  int psb = w * 1024;
  int pw[4];
#pragma unroll
  for (int nt = 0; nt < 4; ++nt)
    pw[nt] = psb + l15 * 64 + (((2 * nt + (quad >> 1)) ^ (l15 & 7)) << 3) + (quad & 1) * 4;
  int pr0 = psb + swz(l15, quad), pr1 = psb + swz(l15, 4 + quad);

  for (int jt = myLo; jt <= myHi; ++jt) {
    int j0 = jt << 6;
    __syncthreads();
    int jn = (jt < myHi) ? ((jt + 1) << 6) : j0;
    int jcn = jn + srow; if (jcn > S_ - 1) jcn = S_ - 1;
    const int4* kp = (const int4*)(kb_base + (size_t)jcn * E_);
    int4 nk0 = kp[0], nk1 = kp[1];
    const int4* vp = (const int4*)(vb_base + jn);
    int4 nv0 = vp[0], nv1 = vp[1];
    *(int4*)&Ks[wl0] = ka0; *(int4*)&Ks[wl1] = ka1;
    *(int4*)&Vt[wl0] = va0; *(int4*)&Vt[wl1] = va1;
    __syncthreads();

    // S^T = K . Q^T : lane holds one q-row (i=l15), 16 j's
    f32x4 st[4];
    __builtin_amdgcn_s_setprio(1);
#pragma unroll
    for (int nt = 0; nt < 4; ++nt) {
      int Rk = nt * 16 + l15;
      bf16x8 kf0 = *(const bf16x8*)&Ks[swz(Rk, quad)];
      bf16x8 kf1 = *(const bf16x8*)&Ks[swz(Rk, 4 + quad)];
      f32x4 s = MFMA16(kf0, qf0, fz);
      st[nt] = MFMA16(kf1, qf1, s);
    }
    __builtin_amdgcn_s_setprio(0);

    bool full = ((j0 + 63 - i0) <= WIN_) && ((i0 + 63 - j0) <= WIN_)
                && (j0 + 63 < S_) && (i0 + 63 < S_);
    float fq = fdi - (float)(j0 + quad * 4);
    if (full) {
#pragma unroll
      for (int nt = 0; nt < 4; ++nt) {
        f32x4 g4 = *(const f32x4*)&gbs[(j0 - jbase) + nt * 16 + quad * 4];
#pragma unroll
        for (int r = 0; r < 4; ++r) {
          float f = fq - (float)(nt * 16 + r);
          float gate = __builtin_amdgcn_rcpf(fmaf(av, g4[r], 1.f));
          float p = __builtin_amdgcn_exp2f(fmaf(f * f, coef2, st[nt][r]) * gate);
          st[nt][r] = p;
        }
      }
    } else {
#pragma unroll
      for (int nt = 0; nt < 4; ++nt) {
        f32x4 g4 = *(const f32x4*)&gbs[(j0 - jbase) + nt * 16 + quad * 4];
#pragma unroll
        for (int r = 0; r < 4; ++r) {
          int j = j0 + nt * 16 + quad * 4 + r;
          float fj = (j < S_) ? (float)j : 1e5f;
          float f = fdi - fj;
          float gate = __builtin_amdgcn_rcpf(fmaf(av, g4[r], 1.f));
          float t = fmaf(f * f, coef2, st[nt][r]) * gate;
          t = (__builtin_fabsf(f) <= 1024.f) ? t : -1e30f;
          float p = __builtin_amdgcn_exp2f(t);
          st[nt][r] = p;
        }
      }
    }

    // P -> bf16 via v_cvt_pk_bf16_f32 (RNE, matches f2bf), swizzled 8B stores
#pragma unroll
    for (int nt = 0; nt < 4; ++nt) {
      unsigned int k0p, k1p;
      asm("v_cvt_pk_bf16_f32 %0, %1, %2" : "=v"(k0p) : "v"(st[nt][0]), "v"(st[nt][1]));
      asm("v_cvt_pk_bf16_f32 %0, %1, %2" : "=v"(k1p) : "v"(st[nt][2]), "v"(st[nt][3]));
      uint2 pk; pk.x = k0p; pk.y = k1p;
      *(uint2*)&Ps[pw[nt]] = pk;
    }
    bf16x8 p0 = *(const bf16x8*)&Ps[pr0];
    bf16x8 p1 = *(const bf16x8*)&Ps[pr1];
    __builtin_amdgcn_s_setprio(1);
#pragma unroll
    for (int nt = 0; nt < 4; ++nt) {
      int Rv = nt * 16 + l15;
      bf16x8 v0 = *(const bf16x8*)&Vt[swz(Rv, quad)];
      bf16x8 v1 = *(const bf16x8*)&Vt[swz(Rv, 4 + quad)];
      Ov[nt] = MFMA16(p0, v0, Ov[nt]);
      Ov[nt] = MFMA16(p1, v1, Ov[nt]);
    }
    // l-row-sum on the MFMA pipe: Lv[r] = sum_j P[i=quad*4+r][j]
    Lv = MFMA16(p0, ones, Lv);
    Lv = MFMA16(p1, ones, Lv);
    __builtin_amdgcn_s_setprio(0);
    ka0 = nk0; ka1 = nk1; va0 = nv0; va1 = nv1;
  }

  // store unnormalized partials (fp32); L rows live in Lv[r] (col-replicated)
#pragma unroll
  for (int r = 0; r < 4; ++r) {
    int irow = i0 + w * 16 + quad * 4 + r;
    if (l15 == 0 && irow < S_)
      Lpart[(size_t)third * BHS_ + (size_t)(b * H_ + h) * S_ + irow] = Lv[r];
  }
#pragma unroll
  for (int r = 0; r < 4; ++r) {
    int irow = i0 + w * 16 + quad * 4 + r;
    if (irow < S_) {
      size_t base = ((size_t)third * BHS_ + (size_t)(b * H_ + h) * S_ + irow) * 64;
#pragma unroll
      for (int nt = 0; nt < 4; ++nt)
        Opart[base + nt * 16 + l15] = Ov[nt][r];
    }
  }
}

// ---------------------------------------------------------------------------
// Combine thirds: o = (O1+O2+O3)/(l1+l2+l3); emit hi/lo bf16, row-major.
// ---------------------------------------------------------------------------
__global__ __launch_bounds__(256) void combine_kernel(
    const float* __restrict__ Opart, const float* __restrict__ Lpart,
    ushort_t* __restrict__ ahi, ushort_t* __restrict__ alo)
{
  int tid = threadIdx.x;
  int gi = blockIdx.x * 16 + (tid >> 4);            // [0, 32784)
  int d4 = tid & 15;
  int b = gi / (H_ * S_);
  int rem = gi - b * (H_ * S_);
  int h = rem / S_;
  int i = rem - h * S_;
  size_t p0 = (size_t)(b * H_ + h) * S_ + i;
  float l = Lpart[p0] + Lpart[p0 + (size_t)BHS_] + Lpart[p0 + 2 * (size_t)BHS_];
  float inv = 1.f / l;
  const float* op = Opart + p0 * 64 + d4 * 4;
  float4 o1 = *(const float4*)op;
  float4 o2 = *(const float4*)(op + (size_t)BHS_ * 64);
  float4 o3 = *(const float4*)(op + 2 * (size_t)BHS_ * 64);
  float o[4] = {(o1.x + o2.x + o3.x) * inv, (o1.y + o2.y + o3.y) * inv,
                (o1.z + o2.z + o3.z) * inv, (o1.w + o2.w + o3.w) * inv};
  ushort4 hi, lo;
  hi.x = f2bf(o[0]); lo.x = f2bf(o[0] - bf2f(hi.x));
  hi.y = f2bf(o[1]); lo.y = f2bf(o[1] - bf2f(hi.y));
  hi.z = f2bf(o[2]); lo.z = f2bf(o[2] - bf2f(hi.z));
  hi.w = f2bf(o[3]); lo.w = f2bf(o[3] - bf2f(hi.w));
  size_t oidx = ((size_t)b * S_ + i) * E_ + h * 64 + d4 * 4;
  *(ushort4*)&ahi[oidx] = hi;
  *(ushort4*)&alo[oidx] = lo;
}

// ---------------------------------------------------------------------------
// Output projection, 64x64 tile, 2x2 waves (32x32 each), BK=64 (8 K-steps),
// 2-term split: C = (Ahi + Alo) @ Whi + bias (fp32 out). Grid (65,8) = 520
// blocks (2 blocks/CU), reg-prefetch.
// ---------------------------------------------------------------------------
__global__ __launch_bounds__(256) void gemm_out_kernel(
    const ushort_t* __restrict__ Ahi, const ushort_t* __restrict__ Alo,
    const ushort_t* __restrict__ Whi, const float* __restrict__ bias,
    float* __restrict__ C)
{
  __shared__ __align__(16) ushort_t AsH[64][72];
  __shared__ __align__(16) ushort_t AsL[64][72];
  __shared__ __align__(16) ushort_t BsW[64][72];
  int tid = threadIdx.x;
  int lane = tid & 63, w = tid >> 6;
  int l15 = lane & 15, quad = lane >> 4;
  int wm = (w & 1) * 32, wn = (w >> 1) * 32;
  int bm = blockIdx.x * 64, bn = blockIdx.y * 64;

  int sr = tid >> 2, sc = (tid & 3) * 16;           // 64 rows x 64 cols
  int am = bm + sr; if (am >= MROWS) am = MROWS - 1;
  const ushort_t* ahp = Ahi + (size_t)am * E_ + sc;
  const ushort_t* alp = Alo + (size_t)am * E_ + sc;
  const ushort_t* bp = Whi + (size_t)(bn + sr) * E_ + sc;

  const f32x4 fz = {0.f, 0.f, 0.f, 0.f};
  f32x4 acc[2][2];
#pragma unroll
  for (int mt = 0; mt < 2; ++mt)
#pragma unroll
    for (int nt = 0; nt < 2; ++nt) acc[mt][nt] = fz;

  int4 ph0 = *(const int4*)ahp, ph1 = *(const int4*)(ahp + 8);
  int4 pl0 = *(const int4*)alp, pl1 = *(const int4*)(alp + 8);
  int4 pb0 = *(const int4*)bp,  pb1 = *(const int4*)(bp + 8);

  for (int k0 = 0; k0 < E_; k0 += 64) {
    __syncthreads();
    int kn = (k0 + 64 < E_) ? (k0 + 64) : k0;
    int4 nh0 = *(const int4*)(ahp + kn), nh1 = *(const int4*)(ahp + kn + 8);
    int4 nl0 = *(const int4*)(alp + kn), nl1 = *(const int4*)(alp + kn + 8);
    int4 nb0 = *(const int4*)(bp + kn),  nb1 = *(const int4*)(bp + kn + 8);
    *(int4*)&AsH[sr][sc] = ph0; *(int4*)&AsH[sr][sc + 8] = ph1;
    *(int4*)&AsL[sr][sc] = pl0; *(int4*)&AsL[sr][sc + 8] = pl1;
    *(int4*)&BsW[sr][sc] = pb0; *(int4*)&BsW[sr][sc + 8] = pb1;
    __syncthreads();
    bf16x8 ah[2][2], al[2][2], bw[2][2];
#pragma unroll
    for (int mt = 0; mt < 2; ++mt) {
      ah[mt][0] = *(const bf16x8*)&AsH[wm + mt * 16 + l15][quad * 8];
      ah[mt][1] = *(const bf16x8*)&AsH[wm + mt * 16 + l15][32 + quad * 8];
      al[mt][0] = *(const bf16x8*)&AsL[wm + mt * 16 + l15][quad * 8];
      al[mt][1] = *(const bf16x8*)&AsL[wm + mt * 16 + l15][32 + quad * 8];
    }
#pragma unroll
    for (int nt = 0; nt < 2; ++nt) {
      bw[nt][0] = *(const bf16x8*)&BsW[wn + nt * 16 + l15][quad * 8];
      bw[nt][1] = *(const bf16x8*)&BsW[wn + nt * 16 + l15][32 + quad * 8];
    }
    __builtin_amdgcn_s_setprio(1);
#pragma unroll
    for (int mt = 0; mt < 2; ++mt)
#pragma unroll
      for (int nt = 0; nt < 2; ++nt) {
        acc[mt][nt] = MFMA16(ah[mt][0], bw[nt][0], acc[mt][nt]);
        acc[mt][nt] = MFMA16(al[mt][0], bw[nt][0], acc[mt][nt]);
        acc[mt][nt] = MFMA16(ah[mt][1], bw[nt][1], acc[mt][nt]);
        acc[mt][nt] = MFMA16(al[mt][1], bw[nt][1], acc[mt][nt]);
      }
    __builtin_amdgcn_s_setprio(0);
    ph0 = nh0; ph1 = nh1; pl0 = nl0; pl1 = nl1; pb0 = nb0; pb1 = nb1;
  }
#pragma unroll
  for (int nt = 0; nt < 2; ++nt) {
    float bb = bias[bn + wn + nt * 16 + l15];
#pragma unroll
    for (int mt = 0; mt < 2; ++mt)
#pragma unroll
      for (int r = 0; r < 4; ++r) {
        int m = bm + wm + mt * 16 + quad * 4 + r;
        if (m < MROWS)
          C[(size_t)m * E_ + bn + wn + nt * 16 + l15] = acc[mt][nt][r] + bb;
      }
  }
}

// ---------------------------------------------------------------------------
extern "C" void kernel_launch(void* const* d_in, const int* in_sizes, int n_in,
                              void* d_out, int out_size, void* d_ws, size_t ws_size,
                              hipStream_t stream) {
  const float* x  = (const float*)d_in[0];
  const float* Wq = (const float*)d_in[1];
  const float* bq = (const float*)d_in[2];
  const float* Wk = (const float*)d_in[3];
  const float* bk = (const float*)d_in[4];
  const float* Wv = (const float*)d_in[5];
  const float* bv = (const float*)d_in[6];
  const float* Wo = (const float*)d_in[7];
  const float* bo = (const float*)d_in[8];
  const float* wg = (const float*)d_in[9];
  const float* bg = (const float*)d_in[10];

  char* p = (char*)d_ws;
  ushort_t* Wt_all = (ushort_t*)p; p += (size_t)3 * E_ * E_ * 2;         // 1.57 MB
  ushort_t* WoHi   = (ushort_t*)p; p += (size_t)E_ * E_ * 2;             // 0.52 MB
  ushort_t* qkb    = (ushort_t*)p; p += (size_t)2 * MROWS * E_ * 2;      // 8.39 MB
  ushort_t* vT     = (ushort_t*)p; p += (size_t)B_ * H_ * 64 * SP_ * 2;  // 4.46 MB
  float*    gacc   = (float*)p;    p += (size_t)2 * GBUFN * 4;           // 33 KB
  float*    Opart  = (float*)p;    p += (size_t)3 * BHS_ * 64 * 4;       // 25.2 MB
  float*    Lpart  = (float*)p;    p += (size_t)3 * BHS_ * 4;            // 0.39 MB
  // xb aliases Opart: xb is dead after qkv; Opart written only in attn.
  ushort_t* xb     = (ushort_t*)Opart;
  // aHi/aLo alias qkb: q/k are dead once attn completes (stream-ordered).
  ushort_t* aHi    = qkb;
  ushort_t* aLo    = qkb + (size_t)MROWS * E_;

  hipLaunchKernelGGL(convert_all_kernel, dim3(3073), dim3(256), 0, stream,
                     x, Wq, Wk, Wv, Wo, xb, Wt_all, WoHi, gacc);
  hipLaunchKernelGGL(gemm_qkv_kernel, dim3(66, 4, 3), dim3(256), 0, stream,
                     xb, Wt_all, bq, bk, bv, wg, qkb, vT, gacc);
  hipLaunchKernelGGL(attn_kernel, dim3(33 * 48), dim3(256), 0, stream,
                     qkb, qkb + (size_t)MROWS * E_, vT, gacc, gacc + GBUFN, bg,
                     Opart, Lpart);
  hipLaunchKernelGGL(combine_kernel, dim3(2049), dim3(256), 0, stream,
                     Opart, Lpart, aHi, aLo);
  hipLaunchKernelGGL(gemm_out_kernel, dim3(65, 8), dim3(256), 0, stream,
                     aHi, aLo, WoHi, bo, (float*)d_out);
}

// Round 5
// 159.679 us; speedup vs baseline: 1.0613x; 1.0014x over previous
//
#include <hip/hip_runtime.h>
#include <cstdint>
#include <cstddef>

#define B_ 2
#define S_ 2049
#define E_ 512
#define H_ 8
#define WIN_ 1024
#define MROWS (B_*S_)     // 4098
#define SP_ 2176          // padded seq for vT cols
#define GBUFN 4104
#define BHS_ (B_*H_*S_)   // 32784

typedef unsigned short ushort_t;
typedef __attribute__((ext_vector_type(8))) short bf16x8;   // 8 bf16 (4 VGPRs)
typedef __attribute__((ext_vector_type(4))) float f32x4;

#define MFMA16(a,b,c) __builtin_amdgcn_mfma_f32_16x16x32_bf16(a,b,c,0,0,0)

__device__ __forceinline__ ushort_t f2bf(float f) {          // RNE fp32->bf16
  unsigned int u = __float_as_uint(f);
  u += 0x7fffu + ((u >> 16) & 1u);
  return (ushort_t)(u >> 16);
}
__device__ __forceinline__ float bf2f(ushort_t h) {
  return __uint_as_float(((unsigned int)h) << 16);
}

// ---------------------------------------------------------------------------
// W-only convert: W [k][n] -> Wt [n][k] bf16 (z<3) / WoHi (z==3); z==3
// blocks also zero the gate accumulators. 1024 blocks. The x->bf16 pass is
// gone — gemm_qkv now reads x fp32 directly and converts in-register.
// ---------------------------------------------------------------------------
__global__ __launch_bounds__(256) void convert_w_kernel(
    const float* __restrict__ W0, const float* __restrict__ W1,
    const float* __restrict__ W2, const float* __restrict__ W3,
    ushort_t* __restrict__ Wt_all, ushort_t* __restrict__ WoHi,
    float* __restrict__ gacc)
{
  __shared__ float tile[32][33];
  int wid = blockIdx.x;                              // 0..1023
  int z = wid >> 8, rem = wid & 255;
  if (z == 3) {
    int gz = rem * 256 + threadIdx.x;
    if (gz < 2 * GBUFN) gacc[gz] = 0.f;
  }
  const float* W = (z == 0) ? W0 : (z == 1) ? W1 : (z == 2) ? W2 : W3;
  int k0 = (rem >> 4) * 32, n0 = (rem & 15) * 32;
  int r = threadIdx.x >> 5, c = threadIdx.x & 31;
#pragma unroll
  for (int i = 0; i < 4; ++i) {
    int rr = r + i * 8;
    tile[rr][c] = W[(size_t)(k0 + rr) * E_ + n0 + c];
  }
  __syncthreads();
#pragma unroll
  for (int i = 0; i < 4; ++i) {
    int rr = r + i * 8;
    float v = tile[c][rr];                       // = W[k0+c][n0+rr]
    size_t dst = (size_t)(n0 + rr) * E_ + k0 + c;
    if (z < 3) Wt_all[(size_t)z * E_ * E_ + dst] = f2bf(v);
    else       WoHi[dst] = f2bf(v);
  }
}

// ---------------------------------------------------------------------------
// QKV projection, 64x128 tile, 2x2 waves (32x64 each), BK=64 (8 K-steps),
// reg-prefetch. A-side reads x fp32 DIRECTLY (contiguous rows, coalesced)
// and converts to bf16 in-register via v_cvt_pk_bf16_f32 at LDS-write time
// — the separate x->bf16 convert pass is deleted. B-side reads Wt bf16.
// z<2: row-major bf16 + fused gate partial dots. z==2: LDS-transpose -> vT.
// ---------------------------------------------------------------------------
__global__ __launch_bounds__(256) void gemm_qkv_kernel(
    const float* __restrict__ x, const ushort_t* __restrict__ Wt_all,
    const float* __restrict__ bq, const float* __restrict__ bk,
    const float* __restrict__ bv, const float* __restrict__ wg,
    ushort_t* __restrict__ qkb, ushort_t* __restrict__ vT,
    float* __restrict__ gacc)
{
  __shared__ __align__(16) ushort_t As[64][72];
  __shared__ __align__(16) ushort_t Bs[128][72];
  int tid = threadIdx.x;
  int lane = tid & 63, w = tid >> 6;
  int l15 = lane & 15, quad = lane >> 4;
  int wm = (w & 1) * 32, wn = (w >> 1) * 64;
  int z = blockIdx.z;
  const ushort_t* Wt = Wt_all + (size_t)z * E_ * E_;
  const float* bias = (z == 0) ? bq : (z == 1) ? bk : bv;
  int bt = blockIdx.x;               // 0..65; 33 i-tiles per batch
  int bg2 = bt / 33;                 // batch b
  int bm = (bt - bg2 * 33) * 64;     // i-tile base within batch
  int bn = blockIdx.y * 128;
  size_t rowbase = (size_t)bg2 * S_;

  int ar = tid >> 2, acq = (tid & 3) * 16;          // A: 64 rows x 64 cols
  int ai = bm + ar; if (ai >= S_) ai = S_ - 1;
  const float* ap = x + (size_t)(rowbase + ai) * E_ + acq;
  int br = tid >> 1, bcq = (tid & 1) * 32;          // B: 128 rows x 64 cols
  const ushort_t* bp = Wt + (size_t)(bn + br) * E_ + bcq;

  const f32x4 fz = {0.f, 0.f, 0.f, 0.f};
  f32x4 acc[2][4];
#pragma unroll
  for (int mt = 0; mt < 2; ++mt)
#pragma unroll
    for (int nt = 0; nt < 4; ++nt) acc[mt][nt] = fz;

  float4 pa0 = *(const float4*)ap,        pa1 = *(const float4*)(ap + 4);
  float4 pa2 = *(const float4*)(ap + 8),  pa3 = *(const float4*)(ap + 12);
  int4 pb0 = *(const int4*)bp,        pb1 = *(const int4*)(bp + 8);
  int4 pb2 = *(const int4*)(bp + 16), pb3 = *(const int4*)(bp + 24);

  for (int k0 = 0; k0 < E_; k0 += 64) {
    __syncthreads();
    int kn = (k0 + 64 < E_) ? (k0 + 64) : k0;
    float4 na0 = *(const float4*)(ap + kn),      na1 = *(const float4*)(ap + kn + 4);
    float4 na2 = *(const float4*)(ap + kn + 8),  na3 = *(const float4*)(ap + kn + 12);
    int4 nb0 = *(const int4*)(bp + kn),      nb1 = *(const int4*)(bp + kn + 8);
    int4 nb2 = *(const int4*)(bp + kn + 16), nb3 = *(const int4*)(bp + kn + 24);
    {
      unsigned int c0, c1, c2, c3, c4, c5, c6, c7;
      asm("v_cvt_pk_bf16_f32 %0, %1, %2" : "=v"(c0) : "v"(pa0.x), "v"(pa0.y));
      asm("v_cvt_pk_bf16_f32 %0, %1, %2" : "=v"(c1) : "v"(pa0.z), "v"(pa0.w));
      asm("v_cvt_pk_bf16_f32 %0, %1, %2" : "=v"(c2) : "v"(pa1.x), "v"(pa1.y));
      asm("v_cvt_pk_bf16_f32 %0, %1, %2" : "=v"(c3) : "v"(pa1.z), "v"(pa1.w));
      asm("v_cvt_pk_bf16_f32 %0, %1, %2" : "=v"(c4) : "v"(pa2.x), "v"(pa2.y));
      asm("v_cvt_pk_bf16_f32 %0, %1, %2" : "=v"(c5) : "v"(pa2.z), "v"(pa2.w));
      asm("v_cvt_pk_bf16_f32 %0, %1, %2" : "=v"(c6) : "v"(pa3.x), "v"(pa3.y));
      asm("v_cvt_pk_bf16_f32 %0, %1, %2" : "=v"(c7) : "v"(pa3.z), "v"(pa3.w));
      int4 A0; A0.x = (int)c0; A0.y = (int)c1; A0.z = (int)c2; A0.w = (int)c3;
      int4 A1; A1.x = (int)c4; A1.y = (int)c5; A1.z = (int)c6; A1.w = (int)c7;
      *(int4*)&As[ar][acq] = A0; *(int4*)&As[ar][acq + 8] = A1;
    }
    *(int4*)&Bs[br][bcq] = pb0;      *(int4*)&Bs[br][bcq + 8] = pb1;
    *(int4*)&Bs[br][bcq + 16] = pb2; *(int4*)&Bs[br][bcq + 24] = pb3;
    __syncthreads();
    bf16x8 a[2][2], bfr[4][2];
#pragma unroll
    for (int mt = 0; mt < 2; ++mt) {
      a[mt][0] = *(const bf16x8*)&As[wm + mt * 16 + l15][quad * 8];
      a[mt][1] = *(const bf16x8*)&As[wm + mt * 16 + l15][32 + quad * 8];
    }
#pragma unroll
    for (int nt = 0; nt < 4; ++nt) {
      bfr[nt][0] = *(const bf16x8*)&Bs[wn + nt * 16 + l15][quad * 8];
      bfr[nt][1] = *(const bf16x8*)&Bs[wn + nt * 16 + l15][32 + quad * 8];
    }
    __builtin_amdgcn_s_setprio(1);
#pragma unroll
    for (int mt = 0; mt < 2; ++mt)
#pragma unroll
      for (int nt = 0; nt < 4; ++nt) {
        acc[mt][nt] = MFMA16(a[mt][0], bfr[nt][0], acc[mt][nt]);
        acc[mt][nt] = MFMA16(a[mt][1], bfr[nt][1], acc[mt][nt]);
      }
    __builtin_amdgcn_s_setprio(0);
    pa0 = na0; pa1 = na1; pa2 = na2; pa3 = na3;
    pb0 = nb0; pb1 = nb1; pb2 = nb2; pb3 = nb3;
  }

  float bb[4];
#pragma unroll
  for (int nt = 0; nt < 4; ++nt) bb[nt] = bias[bn + wn + nt * 16 + l15];

  if (z < 2) {
    ushort_t* C = qkb + (size_t)z * MROWS * E_;
#pragma unroll
    for (int mt = 0; mt < 2; ++mt)
#pragma unroll
      for (int nt = 0; nt < 4; ++nt)
#pragma unroll
        for (int r = 0; r < 4; ++r) {
          int i = bm + wm + mt * 16 + quad * 4 + r;
          if (i < S_)
            C[(rowbase + i) * E_ + bn + wn + nt * 16 + l15] = f2bf(acc[mt][nt][r] + bb[nt]);
        }
    // fused gate partial dots
    const float* wgp = wg + (size_t)z * E_;
    float wv[4];
#pragma unroll
    for (int nt = 0; nt < 4; ++nt) wv[nt] = wgp[bn + wn + nt * 16 + l15];
    float* gp = gacc + (size_t)z * GBUFN;
#pragma unroll
    for (int mt = 0; mt < 2; ++mt)
#pragma unroll
      for (int r = 0; r < 4; ++r) {
        float s = 0.f;
#pragma unroll
        for (int nt = 0; nt < 4; ++nt) s = fmaf(acc[mt][nt][r] + bb[nt], wv[nt], s);
        s += __shfl_xor(s, 1, 16); s += __shfl_xor(s, 2, 16);
        s += __shfl_xor(s, 4, 16); s += __shfl_xor(s, 8, 16);
        int i = bm + wm + mt * 16 + quad * 4 + r;
        if (l15 == 0 && i < S_) atomicAdd(&gp[rowbase + i], s);
      }
  } else {
    // v: LDS transpose (2-way conflicts = free) then coalesced aligned int4
    ushort_t* lt = &Bs[0][0];                    // 64d x 72i tile
    int ti = tid >> 2, tc = (tid & 3) * 16;
#pragma unroll
    for (int hh = 0; hh < 2; ++hh) {
      __syncthreads();
      if ((w >> 1) == hh) {
#pragma unroll
        for (int mt = 0; mt < 2; ++mt)
#pragma unroll
          for (int nt = 0; nt < 4; ++nt) {
            int d = nt * 16 + l15;
#pragma unroll
            for (int r = 0; r < 4; ++r) {
              int il = wm + mt * 16 + quad * 4 + r;
              lt[d * 72 + il] = f2bf(acc[mt][nt][r] + bb[nt]);
            }
          }
      }
      __syncthreads();
      int hg = (bn >> 6) + hh;
      union { int4 q[2]; ushort_t u[16]; } tv;
      tv.q[0] = *(const int4*)&lt[ti * 72 + tc];
      tv.q[1] = *(const int4*)&lt[ti * 72 + tc + 8];
      size_t vrow = ((size_t)(bg2 * H_ + hg) * 64 + ti) * SP_;
#pragma unroll
      for (int c8 = 0; c8 < 2; ++c8) {
        int i2 = bm + tc + c8 * 8;
        if (i2 + 7 < S_) {
          *(int4*)&vT[vrow + i2] = tv.q[c8];
        } else {
#pragma unroll
          for (int e = 0; e < 8; ++e)
            if (i2 + e < S_) vT[vrow + i2 + e] = tv.u[c8 * 8 + e];
        }
      }
    }
  }
}

// ---------------------------------------------------------------------------
// MFMA flash attention, S^T form, fixed-reference softmax, thirds split.
// R4 version (byte-identical): 1584 blocks x 256 thr, XOR-swizzled LDS,
// cvt_pk P-pack, l-row-sum via ones-MFMA, setprio around MFMA clusters.
// ---------------------------------------------------------------------------
__device__ __forceinline__ int swz(int row, int slot) {   // ushort idx in [64][64] tile
  return row * 64 + ((slot ^ (row & 7)) << 3);
}

__global__ __launch_bounds__(256) void attn_kernel(
    const ushort_t* __restrict__ qb, const ushort_t* __restrict__ kb,
    const ushort_t* __restrict__ vT, const float* __restrict__ gq_raw,
    const float* __restrict__ gk_raw, const float* __restrict__ bgate,
    float* __restrict__ Opart, float* __restrict__ Lpart)
{
  __shared__ __align__(16) ushort_t Ks[64 * 64];   // [j][d] swizzled
  __shared__ __align__(16) ushort_t Vt[64 * 64];   // [d][j] swizzled
  __shared__ __align__(16) ushort_t Ps[4 * 16 * 64]; // per-wave P [i][j] swizzled
  __shared__ float gbs[704];

  int tid = threadIdx.x;
  int lane = tid & 63, w = tid >> 6;
  int l15 = lane & 15, quad = lane >> 4;

  // middle-out q-tile order; 48 blocks (16 bh x 3 thirds) per qt
  int sub = blockIdx.x % 48;
  int qidx = blockIdx.x / 48;
  int off = (qidx + 1) >> 1;
  int qt = 16 + ((qidx & 1) ? -off : off);          // 0..32
  int bh = sub & 15, third = sub >> 4;
  int h = bh & 7, b = bh >> 3;
  int i0 = qt * 64;
  const float LOG2E = 1.44269504f;
  const float coef2 = (-0.5f / (512.f * 512.f)) * LOG2E;
  const float QSC = 0.125f * LOG2E;

  // per-thread q-row
  int i = i0 + w * 16 + l15;
  int ic = (i < S_) ? i : S_ - 1;
  bf16x8 qf0 = *(const bf16x8*)&qb[((size_t)(b * S_ + ic)) * E_ + h * 64 + quad * 8];
  bf16x8 qf1 = *(const bf16x8*)&qb[((size_t)(b * S_ + ic)) * E_ + h * 64 + 32 + quad * 8];
#pragma unroll
  for (int e = 0; e < 8; ++e) {                     // fold D^-0.5 * log2e into Q
    qf0[e] = (short)f2bf(bf2f((ushort_t)qf0[e]) * QSC);
    qf1[e] = (short)f2bf(bf2f((ushort_t)qf1[e]) * QSC);
  }
  float av = __expf(-(gq_raw[b * S_ + ic] + bgate[0]));
  float fdi = (i < S_) ? (float)i : -1e5f;

  int jlo = i0 - WIN_; if (jlo < 0) jlo = 0;
  int jt_lo = jlo >> 6;
  int jhi = i0 + 63 + WIN_; if (jhi > S_ - 1) jhi = S_ - 1;
  int jt_hi = jhi >> 6;
  int L = jt_hi - jt_lo + 1;                        // 17..33
  int n0 = (L + 2) / 3, n1 = (L + 1) / 3;
  int myLo = jt_lo + ((third == 0) ? 0 : (third == 1) ? n0 : n0 + n1);
  int cnt = (third == 0) ? n0 : (third == 1) ? n1 : L - n0 - n1;
  int myHi = myLo + cnt - 1;
  int jbase = myLo << 6;
  int nwin = cnt << 6;                              // <= 704

  for (int tt = tid; tt < nwin; tt += 256) {
    int j = jbase + tt; int jc = (j < S_) ? j : S_ - 1;
    gbs[tt] = __expf(-gk_raw[b * S_ + jc]);
  }

  // staging maps: K rows=j, V^T rows=d; both 64x64, 2 int4 per thread.
  // LDS dest slots: row srow, slots 2c / 2c+1 (c = tid&3), XOR-swizzled.
  int srow = tid >> 2, sc4 = tid & 3;
  int scol = sc4 * 16;
  int wl0 = swz(srow, 2 * sc4), wl1 = swz(srow, 2 * sc4 + 1);
  const ushort_t* kb_base = kb + (size_t)b * S_ * E_ + h * 64 + scol;
  const ushort_t* vb_base = vT + ((size_t)(b * H_ + h) * 64 + srow) * SP_ + scol;

  int4 ka0, ka1, va0, va1;
  {
    int jc0 = jbase + srow; if (jc0 > S_ - 1) jc0 = S_ - 1;
    const int4* kp = (const int4*)(kb_base + (size_t)jc0 * E_);
    ka0 = kp[0]; ka1 = kp[1];
    const int4* vp = (const int4*)(vb_base + jbase);
    va0 = vp[0]; va1 = vp[1];
  }

  const f32x4 fz = {0.f, 0.f, 0.f, 0.f};
  f32x4 Ov[4] = {fz, fz, fz, fz};
  const bf16x8 ones = {16256, 16256, 16256, 16256, 16256, 16256, 16256, 16256};
  f32x4 Lv = fz;

  // per-wave P base and swizzled P slot addresses (loop-invariant)
  int psb = w * 1024;
  int pw[4];
#pragma unroll
  for (int nt = 0; nt < 4; ++nt)
    pw[nt] = psb + l15 * 64 + (((2 * nt + (quad >> 1)) ^ (l15 & 7)) << 3) + (quad & 1) * 4;
  int pr0 = psb + swz(l15, quad), pr1 = psb + swz(l15, 4 + quad);

  for (int jt = myLo; jt <= myHi; ++jt) {
    int j0 = jt << 6;
    __syncthreads();
    int jn = (jt < myHi) ? ((jt + 1) << 6) : j0;
    int jcn = jn + srow; if (jcn > S_ - 1) jcn = S_ - 1;
    const int4* kp = (const int4*)(kb_base + (size_t)jcn * E_);
    int4 nk0 = kp[0], nk1 = kp[1];
    const int4* vp = (const int4*)(vb_base + jn);
    int4 nv0 = vp[0], nv1 = vp[1];
    *(int4*)&Ks[wl0] = ka0; *(int4*)&Ks[wl1] = ka1;
    *(int4*)&Vt[wl0] = va0; *(int4*)&Vt[wl1] = va1;
    __syncthreads();

    // S^T = K . Q^T : lane holds one q-row (i=l15), 16 j's
    f32x4 st[4];
    __builtin_amdgcn_s_setprio(1);
#pragma unroll
    for (int nt = 0; nt < 4; ++nt) {
      int Rk = nt * 16 + l15;
      bf16x8 kf0 = *(const bf16x8*)&Ks[swz(Rk, quad)];
      bf16x8 kf1 = *(const bf16x8*)&Ks[swz(Rk, 4 + quad)];
      f32x4 s = MFMA16(kf0, qf0, fz);
      st[nt] = MFMA16(kf1, qf1, s);
    }
    __builtin_amdgcn_s_setprio(0);

    bool full = ((j0 + 63 - i0) <= WIN_) && ((i0 + 63 - j0) <= WIN_)
                && (j0 + 63 < S_) && (i0 + 63 < S_);
    float fq = fdi - (float)(j0 + quad * 4);
    if (full) {
#pragma unroll
      for (int nt = 0; nt < 4; ++nt) {
        f32x4 g4 = *(const f32x4*)&gbs[(j0 - jbase) + nt * 16 + quad * 4];
#pragma unroll
        for (int r = 0; r < 4; ++r) {
          float f = fq - (float)(nt * 16 + r);
          float gate = __builtin_amdgcn_rcpf(fmaf(av, g4[r], 1.f));
          float p = __builtin_amdgcn_exp2f(fmaf(f * f, coef2, st[nt][r]) * gate);
          st[nt][r] = p;
        }
      }
    } else {
#pragma unroll
      for (int nt = 0; nt < 4; ++nt) {
        f32x4 g4 = *(const f32x4*)&gbs[(j0 - jbase) + nt * 16 + quad * 4];
#pragma unroll
        for (int r = 0; r < 4; ++r) {
          int j = j0 + nt * 16 + quad * 4 + r;
          float fj = (j < S_) ? (float)j : 1e5f;
          float f = fdi - fj;
          float gate = __builtin_amdgcn_rcpf(fmaf(av, g4[r], 1.f));
          float t = fmaf(f * f, coef2, st[nt][r]) * gate;
          t = (__builtin_fabsf(f) <= 1024.f) ? t : -1e30f;
          float p = __builtin_amdgcn_exp2f(t);
          st[nt][r] = p;
        }
      }
    }

    // P -> bf16 via v_cvt_pk_bf16_f32 (RNE, matches f2bf), swizzled 8B stores
#pragma unroll
    for (int nt = 0; nt < 4; ++nt) {
      unsigned int k0p, k1p;
      asm("v_cvt_pk_bf16_f32 %0, %1, %2" : "=v"(k0p) : "v"(st[nt][0]), "v"(st[nt][1]));
      asm("v_cvt_pk_bf16_f32 %0, %1, %2" : "=v"(k1p) : "v"(st[nt][2]), "v"(st[nt][3]));
      uint2 pk; pk.x = k0p; pk.y = k1p;
      *(uint2*)&Ps[pw[nt]] = pk;
    }
    bf16x8 p0 = *(const bf16x8*)&Ps[pr0];
    bf16x8 p1 = *(const bf16x8*)&Ps[pr1];
    __builtin_amdgcn_s_setprio(1);
#pragma unroll
    for (int nt = 0; nt < 4; ++nt) {
      int Rv = nt * 16 + l15;
      bf16x8 v0 = *(const bf16x8*)&Vt[swz(Rv, quad)];
      bf16x8 v1 = *(const bf16x8*)&Vt[swz(Rv, 4 + quad)];
      Ov[nt] = MFMA16(p0, v0, Ov[nt]);
      Ov[nt] = MFMA16(p1, v1, Ov[nt]);
    }
    // l-row-sum on the MFMA pipe: Lv[r] = sum_j P[i=quad*4+r][j]
    Lv = MFMA16(p0, ones, Lv);
    Lv = MFMA16(p1, ones, Lv);
    __builtin_amdgcn_s_setprio(0);
    ka0 = nk0; ka1 = nk1; va0 = nv0; va1 = nv1;
  }

  // store unnormalized partials (fp32); L rows live in Lv[r] (col-replicated)
#pragma unroll
  for (int r = 0; r < 4; ++r) {
    int irow = i0 + w * 16 + quad * 4 + r;
    if (l15 == 0 && irow < S_)
      Lpart[(size_t)third * BHS_ + (size_t)(b * H_ + h) * S_ + irow] = Lv[r];
  }
#pragma unroll
  for (int r = 0; r < 4; ++r) {
    int irow = i0 + w * 16 + quad * 4 + r;
    if (irow < S_) {
      size_t base = ((size_t)third * BHS_ + (size_t)(b * H_ + h) * S_ + irow) * 64;
#pragma unroll
      for (int nt = 0; nt < 4; ++nt)
        Opart[base + nt * 16 + l15] = Ov[nt][r];
    }
  }
}

// ---------------------------------------------------------------------------
// Combine thirds: o = (O1+O2+O3)/(l1+l2+l3); emit hi/lo bf16, row-major.
// ---------------------------------------------------------------------------
__global__ __launch_bounds__(256) void combine_kernel(
    const float* __restrict__ Opart, const float* __restrict__ Lpart,
    ushort_t* __restrict__ ahi, ushort_t* __restrict__ alo)
{
  int tid = threadIdx.x;
  int gi = blockIdx.x * 16 + (tid >> 4);            // [0, 32784)
  int d4 = tid & 15;
  int b = gi / (H_ * S_);
  int rem = gi - b * (H_ * S_);
  int h = rem / S_;
  int i = rem - h * S_;
  size_t p0 = (size_t)(b * H_ + h) * S_ + i;
  float l = Lpart[p0] + Lpart[p0 + (size_t)BHS_] + Lpart[p0 + 2 * (size_t)BHS_];
  float inv = 1.f / l;
  const float* op = Opart + p0 * 64 + d4 * 4;
  float4 o1 = *(const float4*)op;
  float4 o2 = *(const float4*)(op + (size_t)BHS_ * 64);
  float4 o3 = *(const float4*)(op + 2 * (size_t)BHS_ * 64);
  float o[4] = {(o1.x + o2.x + o3.x) * inv, (o1.y + o2.y + o3.y) * inv,
                (o1.z + o2.z + o3.z) * inv, (o1.w + o2.w + o3.w) * inv};
  ushort4 hi, lo;
  hi.x = f2bf(o[0]); lo.x = f2bf(o[0] - bf2f(hi.x));
  hi.y = f2bf(o[1]); lo.y = f2bf(o[1] - bf2f(hi.y));
  hi.z = f2bf(o[2]); lo.z = f2bf(o[2] - bf2f(hi.z));
  hi.w = f2bf(o[3]); lo.w = f2bf(o[3] - bf2f(hi.w));
  size_t oidx = ((size_t)b * S_ + i) * E_ + h * 64 + d4 * 4;
  *(ushort4*)&ahi[oidx] = hi;
  *(ushort4*)&alo[oidx] = lo;
}

// ---------------------------------------------------------------------------
// Output projection, 64x64 tile, 2x2 waves (32x32 each), BK=64 (8 K-steps),
// 2-term split: C = (Ahi + Alo) @ Whi + bias (fp32 out). Grid (65,8) = 520
// blocks (2 blocks/CU), reg-prefetch.
// ---------------------------------------------------------------------------
__global__ __launch_bounds__(256) void gemm_out_kernel(
    const ushort_t* __restrict__ Ahi, const ushort_t* __restrict__ Alo,
    const ushort_t* __restrict__ Whi, const float* __restrict__ bias,
    float* __restrict__ C)
{
  __shared__ __align__(16) ushort_t AsH[64][72];
  __shared__ __align__(16) ushort_t AsL[64][72];
  __shared__ __align__(16) ushort_t BsW[64][72];
  int tid = threadIdx.x;
  int lane = tid & 63, w = tid >> 6;
  int l15 = lane & 15, quad = lane >> 4;
  int wm = (w & 1) * 32, wn = (w >> 1) * 32;
  int bm = blockIdx.x * 64, bn = blockIdx.y * 64;

  int sr = tid >> 2, sc = (tid & 3) * 16;           // 64 rows x 64 cols
  int am = bm + sr; if (am >= MROWS) am = MROWS - 1;
  const ushort_t* ahp = Ahi + (size_t)am * E_ + sc;
  const ushort_t* alp = Alo + (size_t)am * E_ + sc;
  const ushort_t* bp = Whi + (size_t)(bn + sr) * E_ + sc;

  const f32x4 fz = {0.f, 0.f, 0.f, 0.f};
  f32x4 acc[2][2];
#pragma unroll
  for (int mt = 0; mt < 2; ++mt)
#pragma unroll
    for (int nt = 0; nt < 2; ++nt) acc[mt][nt] = fz;

  int4 ph0 = *(const int4*)ahp, ph1 = *(const int4*)(ahp + 8);
  int4 pl0 = *(const int4*)alp, pl1 = *(const int4*)(alp + 8);
  int4 pb0 = *(const int4*)bp,  pb1 = *(const int4*)(bp + 8);

  for (int k0 = 0; k0 < E_; k0 += 64) {
    __syncthreads();
    int kn = (k0 + 64 < E_) ? (k0 + 64) : k0;
    int4 nh0 = *(const int4*)(ahp + kn), nh1 = *(const int4*)(ahp + kn + 8);
    int4 nl0 = *(const int4*)(alp + kn), nl1 = *(const int4*)(alp + kn + 8);
    int4 nb0 = *(const int4*)(bp + kn),  nb1 = *(const int4*)(bp + kn + 8);
    *(int4*)&AsH[sr][sc] = ph0; *(int4*)&AsH[sr][sc + 8] = ph1;
    *(int4*)&AsL[sr][sc] = pl0; *(int4*)&AsL[sr][sc + 8] = pl1;
    *(int4*)&BsW[sr][sc] = pb0; *(int4*)&BsW[sr][sc + 8] = pb1;
    __syncthreads();
    bf16x8 ah[2][2], al[2][2], bw[2][2];
#pragma unroll
    for (int mt = 0; mt < 2; ++mt) {
      ah[mt][0] = *(const bf16x8*)&AsH[wm + mt * 16 + l15][quad * 8];
      ah[mt][1] = *(const bf16x8*)&AsH[wm + mt * 16 + l15][32 + quad * 8];
      al[mt][0] = *(const bf16x8*)&AsL[wm + mt * 16 + l15][quad * 8];
      al[mt][1] = *(const bf16x8*)&AsL[wm + mt * 16 + l15][32 + quad * 8];
    }
#pragma unroll
    for (int nt = 0; nt < 2; ++nt) {
      bw[nt][0] = *(const bf16x8*)&BsW[wn + nt * 16 + l15][quad * 8];
      bw[nt][1] = *(const bf16x8*)&BsW[wn + nt * 16 + l15][32 + quad * 8];
    }
    __builtin_amdgcn_s_setprio(1);
#pragma unroll
    for (int mt = 0; mt < 2; ++mt)
#pragma unroll
      for (int nt = 0; nt < 2; ++nt) {
        acc[mt][nt] = MFMA16(ah[mt][0], bw[nt][0], acc[mt][nt]);
        acc[mt][nt] = MFMA16(al[mt][0], bw[nt][0], acc[mt][nt]);
        acc[mt][nt] = MFMA16(ah[mt][1], bw[nt][1], acc[mt][nt]);
        acc[mt][nt] = MFMA16(al[mt][1], bw[nt][1], acc[mt][nt]);
      }
    __builtin_amdgcn_s_setprio(0);
    ph0 = nh0; ph1 = nh1; pl0 = nl0; pl1 = nl1; pb0 = nb0; pb1 = nb1;
  }
#pragma unroll
  for (int nt = 0; nt < 2; ++nt) {
    float bb = bias[bn + wn + nt * 16 + l15];
#pragma unroll
    for (int mt = 0; mt < 2; ++mt)
#pragma unroll
      for (int r = 0; r < 4; ++r) {
        int m = bm + wm + mt * 16 + quad * 4 + r;
        if (m < MROWS)
          C[(size_t)m * E_ + bn + wn + nt * 16 + l15] = acc[mt][nt][r] + bb;
      }
  }
}

// ---------------------------------------------------------------------------
extern "C" void kernel_launch(void* const* d_in, const int* in_sizes, int n_in,
                              void* d_out, int out_size, void* d_ws, size_t ws_size,
                              hipStream_t stream) {
  const float* x  = (const float*)d_in[0];
  const float* Wq = (const float*)d_in[1];
  const float* bq = (const float*)d_in[2];
  const float* Wk = (const float*)d_in[3];
  const float* bk = (const float*)d_in[4];
  const float* Wv = (const float*)d_in[5];
  const float* bv = (const float*)d_in[6];
  const float* Wo = (const float*)d_in[7];
  const float* bo = (const float*)d_in[8];
  const float* wg = (const float*)d_in[9];
  const float* bg = (const float*)d_in[10];

  char* p = (char*)d_ws;
  ushort_t* Wt_all = (ushort_t*)p; p += (size_t)3 * E_ * E_ * 2;         // 1.57 MB
  ushort_t* WoHi   = (ushort_t*)p; p += (size_t)E_ * E_ * 2;             // 0.52 MB
  ushort_t* qkb    = (ushort_t*)p; p += (size_t)2 * MROWS * E_ * 2;      // 8.39 MB
  ushort_t* vT     = (ushort_t*)p; p += (size_t)B_ * H_ * 64 * SP_ * 2;  // 4.46 MB
  float*    gacc   = (float*)p;    p += (size_t)2 * GBUFN * 4;           // 33 KB
  float*    Opart  = (float*)p;    p += (size_t)3 * BHS_ * 64 * 4;       // 25.2 MB
  float*    Lpart  = (float*)p;    p += (size_t)3 * BHS_ * 4;            // 0.39 MB
  // aHi/aLo alias qkb: q/k are dead once attn completes (stream-ordered).
  ushort_t* aHi    = qkb;
  ushort_t* aLo    = qkb + (size_t)MROWS * E_;

  hipLaunchKernelGGL(convert_w_kernel, dim3(1024), dim3(256), 0, stream,
                     Wq, Wk, Wv, Wo, Wt_all, WoHi, gacc);
  hipLaunchKernelGGL(gemm_qkv_kernel, dim3(66, 4, 3), dim3(256), 0, stream,
                     x, Wt_all, bq, bk, bv, wg, qkb, vT, gacc);
  hipLaunchKernelGGL(attn_kernel, dim3(33 * 48), dim3(256), 0, stream,
                     qkb, qkb + (size_t)MROWS * E_, vT, gacc, gacc + GBUFN, bg,
                     Opart, Lpart);
  hipLaunchKernelGGL(combine_kernel, dim3(2049), dim3(256), 0, stream,
                     Opart, Lpart, aHi, aLo);
  hipLaunchKernelGGL(gemm_out_kernel, dim3(65, 8), dim3(256), 0, stream,
                     aHi, aLo, WoHi, bo, (float*)d_out);
}